// Round 2
// baseline (609.657 us; speedup 1.0000x reference)
//
#include <hip/hip_runtime.h>
#include <hip/hip_bf16.h>
#include <stdint.h>

// ---------------------------------------------------------------------------
// SimplifiedSCNN on MI355X.
// Pipeline: scatter(idx last-wins) -> grid/feats -> masks m2/m3/m4 ->
//   conv1 5x5 s1 (f32 in, bf16 out) -> conv 3x3 s2 x3 (bf16 in/out, masked)
//   -> masked mean pool -> tiny MLP.
// Intermediates y1..y4 stored bf16 (storage only; all accumulation fp32).
// Baseline round: validate scatter semantics + bf16 tolerance + structure
// before attempting MFMA implicit-GEMM / conv1-fusion / sparsity compaction.
// ---------------------------------------------------------------------------

static constexpr int B_ = 8, G_ = 512;
static constexpr int NPTS = 8 * 32768;

#define DEVI __device__ __forceinline__

DEVI float bf_lo(unsigned w) { return __uint_as_float(w << 16); }
DEVI float bf_hi(unsigned w) { return __uint_as_float(w & 0xFFFF0000u); }
DEVI unsigned comp(const uint4& v, int i) {
  return i == 0 ? v.x : i == 1 ? v.y : i == 2 ? v.z : v.w;
}
DEVI unsigned short f2bf_bits(float f) {   // round-to-nearest-even bf16
  unsigned u = __float_as_uint(f);
  unsigned r = u + 0x7FFFu + ((u >> 16) & 1u);
  return (unsigned short)(r >> 16);
}
DEVI unsigned pack2(float a, float b) {
  return (unsigned)f2bf_bits(a) | ((unsigned)f2bf_bits(b) << 16);
}

// ---- scatter: last point index wins per cell (matches sequential .set) ----
__global__ __launch_bounds__(256) void k_scatter(const int* __restrict__ coords,
                                                 int* __restrict__ idxg) {
  int i = blockIdx.x * 256 + threadIdx.x;
  if (i >= NPTS) return;
  int b = coords[3 * i], y = coords[3 * i + 1], x = coords[3 * i + 2];
  atomicMax(&idxg[((size_t)b * G_ + y) * G_ + x], i);
}

// ---- gather feats into dense grid ----
__global__ __launch_bounds__(256) void k_grid(const int* __restrict__ idxg,
                                              const float* __restrict__ feats,
                                              float* __restrict__ grid) {
  int i = blockIdx.x * 256 + threadIdx.x;  // B*G*G threads (exact multiple)
  int v = idxg[i];
  grid[i] = (v >= 0) ? feats[v] : 0.0f;
}

// ---- m2 from occupancy ----
__global__ __launch_bounds__(256) void k_m2(const int* __restrict__ idxg,
                                            float* __restrict__ m2) {
  int i = blockIdx.x * 256 + threadIdx.x;  // B*256*256
  int b = i >> 16, r = (i >> 8) & 255, c = i & 255;
  const int* p = idxg + ((size_t)b * G_ + 2 * r) * G_ + 2 * c;
  bool occ = (p[0] >= 0) | (p[1] >= 0) | (p[G_] >= 0) | (p[G_ + 1] >= 0);
  m2[i] = occ ? 1.f : 0.f;
}

// ---- generic 2x2 maxpool for masks ----
template <int WI>
__global__ __launch_bounds__(256) void k_pool_mask(const float* __restrict__ mi,
                                                   float* __restrict__ mo) {
  constexpr int WO = WI / 2;
  int i = blockIdx.x * 256 + threadIdx.x;  // B*WO*WO
  int b = i / (WO * WO);
  int rem = i - b * WO * WO;
  int r = rem / WO, c = rem - r * WO;
  const float* p = mi + ((size_t)b * WI + 2 * r) * WI + 2 * c;
  mo[i] = fmaxf(fmaxf(p[0], p[1]), fmaxf(p[WI], p[WI + 1]));
}

// ---- conv1: 5x5 stride1 pad2, 1 -> 32 ch, relu * m1, bf16 out ----
// block: 16x16 output tile, 256 thr = 64 pixel-quads x 4 co-octets.
__global__ __launch_bounds__(256) void k_conv1(const float* __restrict__ grid,
                                               const int* __restrict__ idxg,
                                               const float* __restrict__ K1f,
                                               __hip_bfloat16* __restrict__ y1) {
  __shared__ float s_g[20][21];   // 16+4 halo, pitch 21 to break bank stride
  __shared__ float s_k[25 * 32];
  const int b = blockIdx.z, ty0 = blockIdx.y * 16, tx0 = blockIdx.x * 16;
  const int t = threadIdx.x;
  for (int i = t; i < 800; i += 256) s_k[i] = K1f[i];
  for (int s = t; s < 420; s += 256) {
    int r = s / 21, c = s - r * 21;
    float v = 0.f;
    int gy = ty0 - 2 + r, gx = tx0 - 2 + c;
    if (c < 20 && gy >= 0 && gy < G_ && gx >= 0 && gx < G_)
      v = grid[((size_t)b * G_ + gy) * G_ + gx];
    s_g[r][c] = v;
  }
  __syncthreads();
  const int c8o = t & 3, q = t >> 2, row = q >> 2, qx = q & 3, co0 = c8o * 8;
  float acc[4][8];
#pragma unroll
  for (int i = 0; i < 4; i++)
#pragma unroll
    for (int j = 0; j < 8; j++) acc[i][j] = 0.f;

  for (int ky = 0; ky < 5; ky++)
#pragma unroll 1
    for (int kx = 0; kx < 5; kx++) {
      const float* kr = &s_k[(ky * 5 + kx) * 32 + co0];
      float4 ka = *(const float4*)kr;
      float4 kb = *(const float4*)(kr + 4);
      float g[4];
#pragma unroll
      for (int i = 0; i < 4; i++) g[i] = s_g[row + ky][qx + 4 * i + kx];
#pragma unroll
      for (int i = 0; i < 4; i++) {
        acc[i][0] += g[i] * ka.x; acc[i][1] += g[i] * ka.y;
        acc[i][2] += g[i] * ka.z; acc[i][3] += g[i] * ka.w;
        acc[i][4] += g[i] * kb.x; acc[i][5] += g[i] * kb.y;
        acc[i][6] += g[i] * kb.z; acc[i][7] += g[i] * kb.w;
      }
    }
  const int oy = ty0 + row;
#pragma unroll
  for (int i = 0; i < 4; i++) {
    int ox = tx0 + qx + 4 * i;
    size_t pix = ((size_t)b * G_ + oy) * G_ + ox;
    float m = (idxg[pix] >= 0) ? 1.f : 0.f;
    unsigned o[4];
#pragma unroll
    for (int cp = 0; cp < 4; cp++)
      o[cp] = pack2(fmaxf(acc[i][2 * cp], 0.f) * m,
                    fmaxf(acc[i][2 * cp + 1], 0.f) * m);
    *(uint4*)(y1 + pix * 32 + co0) = *(uint4*)o;
  }
}

// ---- conv 3x3 stride2 pad1, 32 -> 32 ch, relu * mask, bf16 in/out ----
// block: 16x16 output tile; thread = 4 consecutive-x pixels x 8 out-ch.
// Input tile 33x33x32 bf16 in LDS (69,696 B -> 2 blocks/CU), channel-slot
// swizzle (c8 + (pix>>1)) & 3 to reduce bank conflicts on 64B pixel stride.
// K weights read from global (36 KB, L1/L2 broadcast).
template <int HI>
__global__ __launch_bounds__(256, 2) void k_conv3x3s2(
    const __hip_bfloat16* __restrict__ in, const float* __restrict__ Kw,
    const float* __restrict__ mask, __hip_bfloat16* __restrict__ out) {
  constexpr int WI = HI, HO = HI / 2, WO = WI / 2;
  extern __shared__ __align__(16) unsigned short s_in[];  // [33*33][32] swizzled
  const int b = blockIdx.z, ty0 = blockIdx.y * 16, tx0 = blockIdx.x * 16;
  const int t = threadIdx.x;
  const int iyb = 2 * ty0 - 1, ixb = 2 * tx0 - 1;
  for (int ch = t; ch < 33 * 33 * 4; ch += 256) {
    int pix = ch >> 2, c8 = ch & 3;
    int iy = pix / 33, ix = pix - iy * 33;
    int gy = iyb + iy, gx = ixb + ix;
    uint4 v = make_uint4(0, 0, 0, 0);
    if (gy >= 0 && gy < HI && gx >= 0 && gx < WI)
      v = *(const uint4*)(in + (((size_t)b * HI + gy) * WI + gx) * 32 + c8 * 8);
    *(uint4*)(s_in + pix * 32 + (((c8 + (pix >> 1)) & 3) << 3)) = v;
  }
  __syncthreads();
  const int c8o = t & 3, q = t >> 2, row = q >> 2, qx = q & 3, co0 = c8o * 8;
  float acc[4][8];
#pragma unroll
  for (int i = 0; i < 4; i++)
#pragma unroll
    for (int j = 0; j < 8; j++) acc[i][j] = 0.f;

#pragma unroll 1
  for (int ky = 0; ky < 3; ky++)
#pragma unroll 1
    for (int kx = 0; kx < 3; kx++) {
      const int kk = ky * 3 + kx;
      const int iy = 2 * row + ky;
      for (int cc = 0; cc < 4; cc++) {  // input-channel octet
        uint4 raw[4];
#pragma unroll
        for (int i = 0; i < 4; i++) {
          int ix = 2 * (qx + 4 * i) + kx;
          int pix = iy * 33 + ix;
          raw[i] = *(const uint4*)(s_in + pix * 32 +
                                   (((cc + (pix >> 1)) & 3) << 3));
        }
#pragma unroll
        for (int cp = 0; cp < 4; cp++) {  // channel pair within octet
          const float* k0 = &Kw[((kk * 32 + cc * 8 + 2 * cp) * 32) + co0];
          float4 a0 = *(const float4*)k0;
          float4 a1 = *(const float4*)(k0 + 4);
          float4 b0 = *(const float4*)(k0 + 32);
          float4 b1 = *(const float4*)(k0 + 36);
#pragma unroll
          for (int i = 0; i < 4; i++) {
            unsigned w = comp(raw[i], cp);
            float v0 = bf_lo(w), v1 = bf_hi(w);
            acc[i][0] += v0 * a0.x; acc[i][1] += v0 * a0.y;
            acc[i][2] += v0 * a0.z; acc[i][3] += v0 * a0.w;
            acc[i][4] += v0 * a1.x; acc[i][5] += v0 * a1.y;
            acc[i][6] += v0 * a1.z; acc[i][7] += v0 * a1.w;
            acc[i][0] += v1 * b0.x; acc[i][1] += v1 * b0.y;
            acc[i][2] += v1 * b0.z; acc[i][3] += v1 * b0.w;
            acc[i][4] += v1 * b1.x; acc[i][5] += v1 * b1.y;
            acc[i][6] += v1 * b1.z; acc[i][7] += v1 * b1.w;
          }
        }
      }
    }
  const int oy = ty0 + row;
#pragma unroll
  for (int i = 0; i < 4; i++) {
    int ox = tx0 + qx + 4 * i;
    size_t opix = ((size_t)b * HO + oy) * WO + ox;
    float m = mask[opix];
    unsigned o[4];
#pragma unroll
    for (int cp = 0; cp < 4; cp++)
      o[cp] = pack2(fmaxf(acc[i][2 * cp], 0.f) * m,
                    fmaxf(acc[i][2 * cp + 1], 0.f) * m);
    *(uint4*)(out + opix * 32 + co0) = *(uint4*)o;
  }
}

// ---- masked mean pool over 64x64, per batch ----
__global__ __launch_bounds__(256) void k_pool(const __hip_bfloat16* __restrict__ y4,
                                              const float* __restrict__ m4,
                                              float* __restrict__ pooled) {
  const int b = blockIdx.x, t = threadIdx.x;
  const int c8 = t & 3, g = t >> 2;
  float s[8] = {0, 0, 0, 0, 0, 0, 0, 0};
  for (int p = g; p < 4096; p += 64) {
    uint4 raw = *(const uint4*)(y4 + ((size_t)b * 4096 + p) * 32 + c8 * 8);
#pragma unroll
    for (int cp = 0; cp < 4; cp++) {
      unsigned w = comp(raw, cp);
      s[2 * cp] += bf_lo(w);
      s[2 * cp + 1] += bf_hi(w);
    }
  }
  __shared__ float s_red[64][32];
  __shared__ float s_cnt[256];
#pragma unroll
  for (int j = 0; j < 8; j++) s_red[g][c8 * 8 + j] = s[j];
  float cnt = 0;
  for (int p = t; p < 4096; p += 256) cnt += m4[(size_t)b * 4096 + p];
  s_cnt[t] = cnt;
  __syncthreads();
  for (int st = 32; st > 0; st >>= 1) {
    if (g < st) {
#pragma unroll
      for (int j = 0; j < 8; j++) s_red[g][c8 * 8 + j] += s_red[g + st][c8 * 8 + j];
    }
    __syncthreads();
  }
  for (int st = 128; st > 0; st >>= 1) {
    if (t < st) s_cnt[t] += s_cnt[t + st];
    __syncthreads();
  }
  if (t < 32) pooled[b * 32 + t] = s_red[0][t] / fmaxf(s_cnt[0], 1.f);
}

// ---- final MLP: h = relu(x2@W1+b1)@W2+b2 ; out = relu([pooled,h]@W3+b3) ----
__global__ __launch_bounds__(256) void k_mlp(
    const float* __restrict__ pooled, const float* __restrict__ x2,
    const float* __restrict__ W1, const float* __restrict__ b1,
    const float* __restrict__ W2, const float* __restrict__ b2,
    const float* __restrict__ W3, const float* __restrict__ b3,
    float* __restrict__ outp) {
  __shared__ float s_h1[8 * 64];
  __shared__ float s_z[8 * 64];
  const int t = threadIdx.x;
  for (int i = t; i < 512; i += 256) {
    int bb = i >> 6, j = i & 63;
    float a = b1[j] + x2[bb * 3 + 0] * W1[0 * 64 + j] +
              x2[bb * 3 + 1] * W1[1 * 64 + j] + x2[bb * 3 + 2] * W1[2 * 64 + j];
    s_h1[i] = fmaxf(a, 0.f);
  }
  __syncthreads();
  {
    int bb = t >> 5, ci = t & 31;
    float a = b2[ci];
    for (int k = 0; k < 64; k++) a += s_h1[bb * 64 + k] * W2[k * 32 + ci];
    s_z[bb * 64 + 32 + ci] = a;             // h part (no relu per reference)
    s_z[bb * 64 + ci] = pooled[bb * 32 + ci];  // pooled part
  }
  __syncthreads();
  for (int o = t; o < 1024; o += 256) {
    int bb = o >> 7, j = o & 127;
    float a = b3[j];
    for (int k = 0; k < 64; k++) a += s_z[bb * 64 + k] * W3[k * 128 + j];
    outp[o] = fmaxf(a, 0.f);
  }
}

// ---------------------------------------------------------------------------
extern "C" void kernel_launch(void* const* d_in, const int* in_sizes, int n_in,
                              void* d_out, int out_size, void* d_ws,
                              size_t ws_size, hipStream_t stream) {
  const int* coords = (const int*)d_in[0];
  const float* feats = (const float*)d_in[1];
  const float* x2 = (const float*)d_in[2];
  const float* K1 = (const float*)d_in[3];
  const float* K2 = (const float*)d_in[4];
  const float* K3 = (const float*)d_in[5];
  const float* K4 = (const float*)d_in[6];
  const float* W1 = (const float*)d_in[7];
  const float* b1 = (const float*)d_in[8];
  const float* W2 = (const float*)d_in[9];
  const float* b2 = (const float*)d_in[10];
  const float* W3 = (const float*)d_in[11];
  const float* b3 = (const float*)d_in[12];
  float* outp = (float*)d_out;

  char* ws = (char*)d_ws;
  size_t off = 0;
  auto alloc = [&](size_t bytes) {
    char* p = ws + off;
    off += (bytes + 255) & ~(size_t)255;
    return p;
  };
  int* idxg = (int*)alloc(8ull * 512 * 512 * 4);
  float* grid = (float*)alloc(8ull * 512 * 512 * 4);
  __hip_bfloat16* y1 = (__hip_bfloat16*)alloc(8ull * 512 * 512 * 32 * 2);
  __hip_bfloat16* y2 = (__hip_bfloat16*)alloc(8ull * 256 * 256 * 32 * 2);
  __hip_bfloat16* y3 = (__hip_bfloat16*)alloc(8ull * 128 * 128 * 32 * 2);
  __hip_bfloat16* y4 = (__hip_bfloat16*)alloc(8ull * 64 * 64 * 32 * 2);
  float* m2 = (float*)alloc(8ull * 256 * 256 * 4);
  float* m3 = (float*)alloc(8ull * 128 * 128 * 4);
  float* m4 = (float*)alloc(8ull * 64 * 64 * 4);
  float* pooled = (float*)alloc(8 * 32 * 4);
  (void)ws_size; (void)in_sizes; (void)n_in; (void)out_size;

  hipMemsetAsync(idxg, 0xFF, 8ull * 512 * 512 * 4, stream);  // idx = -1

  k_scatter<<<NPTS / 256, 256, 0, stream>>>(coords, idxg);
  k_grid<<<(8 * 512 * 512) / 256, 256, 0, stream>>>(idxg, feats, grid);
  k_m2<<<(8 * 256 * 256) / 256, 256, 0, stream>>>(idxg, m2);
  k_pool_mask<256><<<(8 * 128 * 128) / 256, 256, 0, stream>>>(m2, m3);
  k_pool_mask<128><<<(8 * 64 * 64) / 256, 256, 0, stream>>>(m3, m4);

  k_conv1<<<dim3(32, 32, 8), 256, 0, stream>>>(grid, idxg, K1, y1);

  const int shbytes = 33 * 33 * 32 * 2;  // 69,696 B dynamic LDS
  (void)hipFuncSetAttribute(reinterpret_cast<const void*>(&k_conv3x3s2<512>),
                            hipFuncAttributeMaxDynamicSharedMemorySize, shbytes);
  (void)hipFuncSetAttribute(reinterpret_cast<const void*>(&k_conv3x3s2<256>),
                            hipFuncAttributeMaxDynamicSharedMemorySize, shbytes);
  (void)hipFuncSetAttribute(reinterpret_cast<const void*>(&k_conv3x3s2<128>),
                            hipFuncAttributeMaxDynamicSharedMemorySize, shbytes);

  k_conv3x3s2<512><<<dim3(16, 16, 8), 256, shbytes, stream>>>(y1, K2, m2, y2);
  k_conv3x3s2<256><<<dim3(8, 8, 8), 256, shbytes, stream>>>(y2, K3, m3, y3);
  k_conv3x3s2<128><<<dim3(4, 4, 8), 256, shbytes, stream>>>(y3, K4, m4, y4);

  k_pool<<<8, 256, 0, stream>>>(y4, m4, pooled);
  k_mlp<<<1, 256, 0, stream>>>(pooled, x2, W1, b1, W2, b2, W3, b3, outp);
}

// Round 5
// 246.078 us; speedup vs baseline: 2.4775x; 2.4775x over previous
//
#include <hip/hip_runtime.h>
#include <hip/hip_bf16.h>
#include <stdint.h>

// ---------------------------------------------------------------------------
// SimplifiedSCNN on MI355X — round 4.
// conv2/3/4: MFMA implicit-GEMM (round-3, unvalidated -> validation target).
// conv1: NEW — also MFMA implicit-GEMM, K=25 taps padded to 32, with f32
// input split into bf16 hi+lo (D = Ah*Bh + Ah*Bl + Al*Bh) to preserve
// f32-grade accuracy (dropped Al*Bl ~ 2^-18 relative).
// All MFMA kernels share the same A/B/C fragment-layout assumptions, so a
// layout error fails everything at once (attributable), and per-dispatch
// counters attribute performance individually.
// ---------------------------------------------------------------------------

static constexpr int G_ = 512;
static constexpr int NPTS = 8 * 32768;

#define DEVI __device__ __forceinline__

typedef __attribute__((ext_vector_type(8))) short bf16x8;
typedef __attribute__((ext_vector_type(4))) float f32x4;

DEVI float bf_lo(unsigned w) { return __uint_as_float(w << 16); }
DEVI float bf_hi(unsigned w) { return __uint_as_float(w & 0xFFFF0000u); }
DEVI unsigned comp(const uint4& v, int i) {
  return i == 0 ? v.x : i == 1 ? v.y : i == 2 ? v.z : v.w;
}
DEVI unsigned short f2bf_bits(float f) {   // round-to-nearest-even bf16
  unsigned u = __float_as_uint(f);
  unsigned r = u + 0x7FFFu + ((u >> 16) & 1u);
  return (unsigned short)(r >> 16);
}

// ---- scatter: last point index wins per cell (matches sequential .set) ----
__global__ __launch_bounds__(256) void k_scatter(const int* __restrict__ coords,
                                                 int* __restrict__ idxg) {
  int i = blockIdx.x * 256 + threadIdx.x;
  if (i >= NPTS) return;
  int b = coords[3 * i], y = coords[3 * i + 1], x = coords[3 * i + 2];
  atomicMax(&idxg[((size_t)b * G_ + y) * G_ + x], i);
}

// ---- gather feats into dense grid ----
__global__ __launch_bounds__(256) void k_grid(const int* __restrict__ idxg,
                                              const float* __restrict__ feats,
                                              float* __restrict__ grid) {
  int i = blockIdx.x * 256 + threadIdx.x;
  int v = idxg[i];
  grid[i] = (v >= 0) ? feats[v] : 0.0f;
}

// ---- m2 from occupancy ----
__global__ __launch_bounds__(256) void k_m2(const int* __restrict__ idxg,
                                            float* __restrict__ m2) {
  int i = blockIdx.x * 256 + threadIdx.x;  // B*256*256
  int b = i >> 16, r = (i >> 8) & 255, c = i & 255;
  const int* p = idxg + ((size_t)b * G_ + 2 * r) * G_ + 2 * c;
  bool occ = (p[0] >= 0) | (p[1] >= 0) | (p[G_] >= 0) | (p[G_ + 1] >= 0);
  m2[i] = occ ? 1.f : 0.f;
}

// ---- generic 2x2 maxpool for masks ----
template <int WI>
__global__ __launch_bounds__(256) void k_pool_mask(const float* __restrict__ mi,
                                                   float* __restrict__ mo) {
  constexpr int WO = WI / 2;
  int i = blockIdx.x * 256 + threadIdx.x;  // B*WO*WO
  int b = i / (WO * WO);
  int rem = i - b * WO * WO;
  int r = rem / WO, c = rem - r * WO;
  const float* p = mi + ((size_t)b * WI + 2 * r) * WI + 2 * c;
  mo[i] = fmaxf(fmaxf(p[0], p[1]), fmaxf(p[WI], p[WI + 1]));
}

// ---- conv1 via MFMA: 5x5 s1 p2, 1 -> 32 ch, relu * m1, bf16 out ----
// GEMM: M=16 px (one row segment), N=32 co (2 halves), K=25 taps pad to 32.
// f32 grid split hi+lo bf16; D = Ah*Bh + Ah*Bl + Al*Bh (f32-grade accuracy).
// Block: 4 waves, wave w -> row R+w; 16 segments over a 256-px x-half.
// LDS: 8x264 f32 input tile (rows R-2..R+5, cols x0-2..x0+257) + B frags.
__global__ __launch_bounds__(256) void k_conv1_mfma(
    const float* __restrict__ grid, const int* __restrict__ idxg,
    const float* __restrict__ K1f, __hip_bfloat16* __restrict__ y1) {
  constexpr int PITCH = 264;
  __shared__ unsigned short s_bh[2 * 64 * 8], s_bl[2 * 64 * 8];  // 4 KB
  __shared__ float s_tile[8 * PITCH];                            // 8.25 KB

  const int t = threadIdx.x;
  const int b = blockIdx.z, R = blockIdx.y * 4, x0 = blockIdx.x * 256;

  // --- pack B (hi/lo) into frag layout: lane=co%16 + 16*g, j -> k=8g+j ---
  for (int e = t; e < 128; e += 256) {
    int h = e >> 6, ln = e & 63;
    int g2 = ln >> 4, co = h * 16 + (ln & 15);
#pragma unroll
    for (int j = 0; j < 8; j++) {
      int k = 8 * g2 + j;
      float v = (k < 25) ? K1f[k * 32 + co] : 0.f;
      unsigned short hb = f2bf_bits(v);
      s_bh[e * 8 + j] = hb;
      s_bl[e * 8 + j] = f2bf_bits(v - __uint_as_float((unsigned)hb << 16));
    }
  }
  // --- stage input tile (zero-padded) ---
  for (int i = t; i < 8 * 260; i += 256) {
    int rr = i / 260, cc = i - rr * 260;
    int gy = R - 2 + rr, gx = x0 - 2 + cc;
    float v = 0.f;
    if (gy >= 0 && gy < G_ && gx >= 0 && gx < G_)
      v = grid[((size_t)b * G_ + gy) * G_ + gx];
    s_tile[rr * PITCH + cc] = v;
  }
  __syncthreads();

  const int lane = t & 63, w = t >> 6;
  const int r = lane & 15, g = lane >> 4;
  bf16x8 bh[2], bl[2];
#pragma unroll
  for (int h = 0; h < 2; h++) {
    bh[h] = *(const bf16x8*)&s_bh[(h * 64 + lane) * 8];
    bl[h] = *(const bf16x8*)&s_bl[(h * 64 + lane) * 8];
  }
  // per-lane tap offsets (invariant across segments)
  int toff[8]; bool tval[8];
#pragma unroll
  for (int j = 0; j < 8; j++) {
    int k = 8 * g + j;
    tval[j] = (k < 25);
    int kq = tval[j] ? k : 0;
    int ky = kq / 5, kx = kq - 5 * ky;
    toff[j] = (w + ky) * PITCH + kx;
  }

  const int oy = R + w;
  const size_t rowo = ((size_t)b * G_ + oy) * G_;

  for (int s = 0; s < 16; s++) {
    const int oxl = s * 16;
    bf16x8 ahv, alv;
#pragma unroll
    for (int j = 0; j < 8; j++) {
      float v = tval[j] ? s_tile[toff[j] + oxl + r] : 0.f;
      unsigned short hb = f2bf_bits(v);
      ahv[j] = (short)hb;
      alv[j] = (short)f2bf_bits(v - __uint_as_float((unsigned)hb << 16));
    }
    f32x4 acc0 = {0.f, 0.f, 0.f, 0.f}, acc1 = {0.f, 0.f, 0.f, 0.f};
    acc0 = __builtin_amdgcn_mfma_f32_16x16x32_bf16(ahv, bh[0], acc0, 0, 0, 0);
    acc1 = __builtin_amdgcn_mfma_f32_16x16x32_bf16(ahv, bh[1], acc1, 0, 0, 0);
    acc0 = __builtin_amdgcn_mfma_f32_16x16x32_bf16(ahv, bl[0], acc0, 0, 0, 0);
    acc1 = __builtin_amdgcn_mfma_f32_16x16x32_bf16(ahv, bl[1], acc1, 0, 0, 0);
    acc0 = __builtin_amdgcn_mfma_f32_16x16x32_bf16(alv, bh[0], acc0, 0, 0, 0);
    acc1 = __builtin_amdgcn_mfma_f32_16x16x32_bf16(alv, bh[1], acc1, 0, 0, 0);

#pragma unroll
    for (int q = 0; q < 4; q++) {
      const size_t opix = rowo + (x0 + oxl + g * 4 + q);
      const float m = (idxg[opix] >= 0) ? 1.f : 0.f;
      unsigned short* op = (unsigned short*)(y1 + opix * 32);
      op[r] = f2bf_bits(fmaxf(acc0[q], 0.f) * m);
      op[r + 16] = f2bf_bits(fmaxf(acc1[q], 0.f) * m);
    }
  }
}

// ---- conv 3x3 stride2 pad1, 32 -> 32 ch via MFMA implicit-GEMM ----
// Block = 4 waves; wave w handles output row oy = blockIdx.y*4+w, iterating
// 16-pixel segments. Per segment: 9 A-frag dwordx4 global loads + 18 MFMA.
// A-frag (16x16x32 bf16): row=lane&15 -> pixel, k=8*(lane>>4)+j -> in-ch.
// B-frag: col=lane&15 -> co (within half), k=8*(lane>>4)+j -> ci; packed to
// LDS once per block, held in VGPRs.
// C/D: col=lane&15 -> co, row=(lane>>4)*4+reg -> pixel. [m89-verified layout]
template <int HI, int SEGS>
__global__ __launch_bounds__(256) void k_conv3x3s2_mfma(
    const __hip_bfloat16* __restrict__ in, const float* __restrict__ Kw,
    const float* __restrict__ mask, __hip_bfloat16* __restrict__ out) {
  constexpr int WI = HI, HO = HI / 2, WO = WI / 2;
  constexpr int NSEG = WO / 16 / SEGS;
  __shared__ unsigned short s_pw[9 * 2 * 64 * 8];  // 18,432 B

  const int t = threadIdx.x;
  // --- pre-pack weights into B-frag layout ---
  for (int e = t; e < 1152; e += 256) {
    int kk = e >> 7;            // e / 128
    int rem = e & 127;
    int h = rem >> 6, ln = rem & 63;
    int g = ln >> 4, co = h * 16 + (ln & 15);
#pragma unroll
    for (int j = 0; j < 8; j++)
      s_pw[e * 8 + j] = f2bf_bits(Kw[((kk * 32) + 8 * g + j) * 32 + co]);
  }
  __syncthreads();

  const int lane = t & 63, w = t >> 6;
  const int r = lane & 15, g = lane >> 4;
  bf16x8 bw[9][2];
#pragma unroll
  for (int kk = 0; kk < 9; kk++)
#pragma unroll
    for (int h = 0; h < 2; h++)
      bw[kk][h] = *(const bf16x8*)&s_pw[((kk * 2 + h) * 64 + lane) * 8];

  const int b = blockIdx.z;
  const int oy = blockIdx.y * 4 + w;
  const int ox_base = blockIdx.x * (WO / SEGS);
  const __hip_bfloat16* inb = in + (size_t)b * HI * WI * 32;

  for (int s = 0; s < NSEG; s++) {
    const int ox0 = ox_base + s * 16;
    f32x4 acc0 = {0.f, 0.f, 0.f, 0.f}, acc1 = {0.f, 0.f, 0.f, 0.f};
#pragma unroll
    for (int ky = 0; ky < 3; ky++) {
      const int iy = 2 * oy + ky - 1;  // in [-1, HI-1]
      const __hip_bfloat16* rowp = inb + (size_t)(iy < 0 ? 0 : iy) * WI * 32;
#pragma unroll
      for (int kx = 0; kx < 3; kx++) {
        const int ix = 2 * (ox0 + r) + kx - 1;  // in [-1, WI-1]
        uint4 v = *(const uint4*)(rowp + (size_t)(ix < 0 ? 0 : ix) * 32 + g * 8);
        if ((iy | ix) < 0) { v.x = 0; v.y = 0; v.z = 0; v.w = 0; }
        bf16x8 a = *reinterpret_cast<const bf16x8*>(&v);
        acc0 = __builtin_amdgcn_mfma_f32_16x16x32_bf16(a, bw[ky * 3 + kx][0],
                                                       acc0, 0, 0, 0);
        acc1 = __builtin_amdgcn_mfma_f32_16x16x32_bf16(a, bw[ky * 3 + kx][1],
                                                       acc1, 0, 0, 0);
      }
    }
    // epilogue: relu * mask, bf16 stores
    const size_t rowo = ((size_t)b * HO + oy) * WO;
#pragma unroll
    for (int q = 0; q < 4; q++) {
      const int rr = g * 4 + q;
      const size_t opix = rowo + (ox0 + rr);
      const float m = mask[opix];
      unsigned short* op = (unsigned short*)(out + opix * 32);
      op[r] = f2bf_bits(fmaxf(acc0[q], 0.f) * m);
      op[r + 16] = f2bf_bits(fmaxf(acc1[q], 0.f) * m);
    }
  }
}

// ---- masked mean pool over 64x64, per batch ----
__global__ __launch_bounds__(256) void k_pool(const __hip_bfloat16* __restrict__ y4,
                                              const float* __restrict__ m4,
                                              float* __restrict__ pooled) {
  const int b = blockIdx.x, t = threadIdx.x;
  const int c8 = t & 3, g = t >> 2;
  float s[8] = {0, 0, 0, 0, 0, 0, 0, 0};
  for (int p = g; p < 4096; p += 64) {
    uint4 raw = *(const uint4*)(y4 + ((size_t)b * 4096 + p) * 32 + c8 * 8);
#pragma unroll
    for (int cp = 0; cp < 4; cp++) {
      unsigned w = comp(raw, cp);
      s[2 * cp] += bf_lo(w);
      s[2 * cp + 1] += bf_hi(w);
    }
  }
  __shared__ float s_red[64][32];
  __shared__ float s_cnt[256];
#pragma unroll
  for (int j = 0; j < 8; j++) s_red[g][c8 * 8 + j] = s[j];
  float cnt = 0;
  for (int p = t; p < 4096; p += 256) cnt += m4[(size_t)b * 4096 + p];
  s_cnt[t] = cnt;
  __syncthreads();
  for (int st = 32; st > 0; st >>= 1) {
    if (g < st) {
#pragma unroll
      for (int j = 0; j < 8; j++) s_red[g][c8 * 8 + j] += s_red[g + st][c8 * 8 + j];
    }
    __syncthreads();
  }
  for (int st = 128; st > 0; st >>= 1) {
    if (t < st) s_cnt[t] += s_cnt[t + st];
    __syncthreads();
  }
  if (t < 32) pooled[b * 32 + t] = s_red[0][t] / fmaxf(s_cnt[0], 1.f);
}

// ---- final MLP ----
__global__ __launch_bounds__(256) void k_mlp(
    const float* __restrict__ pooled, const float* __restrict__ x2,
    const float* __restrict__ W1, const float* __restrict__ b1,
    const float* __restrict__ W2, const float* __restrict__ b2,
    const float* __restrict__ W3, const float* __restrict__ b3,
    float* __restrict__ outp) {
  __shared__ float s_h1[8 * 64];
  __shared__ float s_z[8 * 64];
  const int t = threadIdx.x;
  for (int i = t; i < 512; i += 256) {
    int bb = i >> 6, j = i & 63;
    float a = b1[j] + x2[bb * 3 + 0] * W1[0 * 64 + j] +
              x2[bb * 3 + 1] * W1[1 * 64 + j] + x2[bb * 3 + 2] * W1[2 * 64 + j];
    s_h1[i] = fmaxf(a, 0.f);
  }
  __syncthreads();
  {
    int bb = t >> 5, ci = t & 31;
    float a = b2[ci];
    for (int k = 0; k < 64; k++) a += s_h1[bb * 64 + k] * W2[k * 32 + ci];
    s_z[bb * 64 + 32 + ci] = a;                // h part (no relu per reference)
    s_z[bb * 64 + ci] = pooled[bb * 32 + ci];  // pooled part
  }
  __syncthreads();
  for (int o = t; o < 1024; o += 256) {
    int bb = o >> 7, j = o & 127;
    float a = b3[j];
    for (int k = 0; k < 64; k++) a += s_z[bb * 64 + k] * W3[k * 128 + j];
    outp[o] = fmaxf(a, 0.f);
  }
}

// ---------------------------------------------------------------------------
extern "C" void kernel_launch(void* const* d_in, const int* in_sizes, int n_in,
                              void* d_out, int out_size, void* d_ws,
                              size_t ws_size, hipStream_t stream) {
  const int* coords = (const int*)d_in[0];
  const float* feats = (const float*)d_in[1];
  const float* x2 = (const float*)d_in[2];
  const float* K1 = (const float*)d_in[3];
  const float* K2 = (const float*)d_in[4];
  const float* K3 = (const float*)d_in[5];
  const float* K4 = (const float*)d_in[6];
  const float* W1 = (const float*)d_in[7];
  const float* b1 = (const float*)d_in[8];
  const float* W2 = (const float*)d_in[9];
  const float* b2 = (const float*)d_in[10];
  const float* W3 = (const float*)d_in[11];
  const float* b3 = (const float*)d_in[12];
  float* outp = (float*)d_out;

  char* ws = (char*)d_ws;
  size_t off = 0;
  auto alloc = [&](size_t bytes) {
    char* p = ws + off;
    off += (bytes + 255) & ~(size_t)255;
    return p;
  };
  int* idxg = (int*)alloc(8ull * 512 * 512 * 4);
  float* grid = (float*)alloc(8ull * 512 * 512 * 4);
  __hip_bfloat16* y1 = (__hip_bfloat16*)alloc(8ull * 512 * 512 * 32 * 2);
  __hip_bfloat16* y2 = (__hip_bfloat16*)alloc(8ull * 256 * 256 * 32 * 2);
  __hip_bfloat16* y3 = (__hip_bfloat16*)alloc(8ull * 128 * 128 * 32 * 2);
  __hip_bfloat16* y4 = (__hip_bfloat16*)alloc(8ull * 64 * 64 * 32 * 2);
  float* m2 = (float*)alloc(8ull * 256 * 256 * 4);
  float* m3 = (float*)alloc(8ull * 128 * 128 * 4);
  float* m4 = (float*)alloc(8ull * 64 * 64 * 4);
  float* pooled = (float*)alloc(8 * 32 * 4);
  (void)ws_size; (void)in_sizes; (void)n_in; (void)out_size;

  hipMemsetAsync(idxg, 0xFF, 8ull * 512 * 512 * 4, stream);  // idx = -1

  k_scatter<<<NPTS / 256, 256, 0, stream>>>(coords, idxg);
  k_grid<<<(8 * 512 * 512) / 256, 256, 0, stream>>>(idxg, feats, grid);
  k_m2<<<(8 * 256 * 256) / 256, 256, 0, stream>>>(idxg, m2);
  k_pool_mask<256><<<(8 * 128 * 128) / 256, 256, 0, stream>>>(m2, m3);
  k_pool_mask<128><<<(8 * 64 * 64) / 256, 256, 0, stream>>>(m3, m4);

  // conv1 MFMA: grid (x-halves, row-quads, batch)
  k_conv1_mfma<<<dim3(2, 128, 8), 256, 0, stream>>>(grid, idxg, K1, y1);

  // MFMA implicit-GEMM convs. grid = (SEGS, HO/4, B); 4 waves/block, 1 row
  // per wave, NSEG 16-px segments per wave.
  k_conv3x3s2_mfma<512, 2><<<dim3(2, 64, 8), 256, 0, stream>>>(y1, K2, m2, y2);
  k_conv3x3s2_mfma<256, 2><<<dim3(2, 32, 8), 256, 0, stream>>>(y2, K3, m3, y3);
  k_conv3x3s2_mfma<128, 2><<<dim3(2, 16, 8), 256, 0, stream>>>(y3, K4, m4, y4);

  k_pool<<<8, 256, 0, stream>>>(y4, m4, pooled);
  k_mlp<<<1, 256, 0, stream>>>(pooled, x2, W1, b1, W2, b2, W3, b3, outp);
}

// Round 8
// 237.072 us; speedup vs baseline: 2.5716x; 1.0380x over previous
//
#include <hip/hip_runtime.h>
#include <hip/hip_bf16.h>
#include <stdint.h>

// ---------------------------------------------------------------------------
// SimplifiedSCNN on MI355X — round 6 kernel (3rd submit; GPU timeouts).
//  1. grid stored as packed (bf16_hi | bf16_lo<<16) u32, split hoisted into
//     k_grid: conv1 inner loop loses ~48 VALU ops/segment (same numerics).
//  2. One-time k_packw packs all conv weights into B-frag tables in ws;
//     conv kernels load frags straight from global (coalesced, L2-resident).
//     conv2/3/4 become LDS-free; conv4 runs 1-wave blocks (2048 blocks).
//  3. m2/m3/m4 fused into one k_masks kernel (LDS cascade).
// ---------------------------------------------------------------------------

static constexpr int G_ = 512;
static constexpr int NPTS = 8 * 32768;

#define DEVI __device__ __forceinline__

typedef __attribute__((ext_vector_type(8))) short bf16x8;
typedef __attribute__((ext_vector_type(4))) float f32x4;
typedef __attribute__((ext_vector_type(4))) unsigned u32x4;

DEVI float bf_lo(unsigned w) { return __uint_as_float(w << 16); }
DEVI float bf_hi(unsigned w) { return __uint_as_float(w & 0xFFFF0000u); }
DEVI unsigned comp(const uint4& v, int i) {
  return i == 0 ? v.x : i == 1 ? v.y : i == 2 ? v.z : v.w;
}
DEVI unsigned short f2bf_bits(float f) {   // round-to-nearest-even bf16
  unsigned u = __float_as_uint(f);
  unsigned r = u + 0x7FFFu + ((u >> 16) & 1u);
  return (unsigned short)(r >> 16);
}

// ---- scatter: last point index wins per cell (matches sequential .set) ----
__global__ __launch_bounds__(256) void k_scatter(const int* __restrict__ coords,
                                                 int* __restrict__ idxg) {
  int i = blockIdx.x * 256 + threadIdx.x;
  if (i >= NPTS) return;
  int b = coords[3 * i], y = coords[3 * i + 1], x = coords[3 * i + 2];
  atomicMax(&idxg[((size_t)b * G_ + y) * G_ + x], i);
}

// ---- gather feats into grid, pre-split into (bf16_hi | bf16_lo<<16) ----
__global__ __launch_bounds__(256) void k_grid(const int* __restrict__ idxg,
                                              const float* __restrict__ feats,
                                              unsigned* __restrict__ grid2) {
  int i = blockIdx.x * 256 + threadIdx.x;
  int v = idxg[i];
  float f = (v >= 0) ? feats[v] : 0.0f;
  unsigned short hb = f2bf_bits(f);
  unsigned short lb = f2bf_bits(f - __uint_as_float((unsigned)hb << 16));
  grid2[i] = (unsigned)hb | ((unsigned)lb << 16);
}

// ---- one-time weight pack into B-frag tables ----
// Layout (matches frag read): elem e=(kk*2+h)*64+lane, j=0..7 -> k=8*(lane>>4)+j,
// co = h*16 + (lane&15).
__global__ __launch_bounds__(256) void k_packw(
    const float* __restrict__ K1f, const float* __restrict__ K2,
    const float* __restrict__ K3, const float* __restrict__ K4,
    unsigned short* __restrict__ pw1h, unsigned short* __restrict__ pw1l,
    unsigned short* __restrict__ pw2, unsigned short* __restrict__ pw3,
    unsigned short* __restrict__ pw4) {
  const int t = threadIdx.x;
  if (t < 128) {  // K1: 25 taps padded to 32, hi/lo split
    int h = t >> 6, ln = t & 63;
    int g2 = ln >> 4, co = h * 16 + (ln & 15);
#pragma unroll
    for (int j = 0; j < 8; j++) {
      int k = 8 * g2 + j;
      float v = (k < 25) ? K1f[k * 32 + co] : 0.f;
      unsigned short hb = f2bf_bits(v);
      pw1h[t * 8 + j] = hb;
      pw1l[t * 8 + j] = f2bf_bits(v - __uint_as_float((unsigned)hb << 16));
    }
  }
  const float* Ks[3] = {K2, K3, K4};
  unsigned short* ps[3] = {pw2, pw3, pw4};
  for (int m = 0; m < 3; m++)
    for (int e = t; e < 1152; e += 256) {
      int kk = e >> 7, rem = e & 127;
      int h = rem >> 6, ln = rem & 63;
      int g2 = ln >> 4, co = h * 16 + (ln & 15);
#pragma unroll
      for (int j = 0; j < 8; j++)
        ps[m][e * 8 + j] = f2bf_bits(Ks[m][((kk * 32) + 8 * g2 + j) * 32 + co]);
    }
}

// ---- fused mask chain: m2 (from idxg) -> m3 -> m4 ----
__global__ __launch_bounds__(256) void k_masks(const int* __restrict__ idxg,
                                               float* __restrict__ m2,
                                               float* __restrict__ m3,
                                               float* __restrict__ m4) {
  __shared__ float sm2[32][32];
  __shared__ float sm3[16][16];
  const int b = blockIdx.z, ty0 = blockIdx.y * 32, tx0 = blockIdx.x * 32;
  const int t = threadIdx.x;
  for (int i = t; i < 1024; i += 256) {
    int r = i >> 5, c = i & 31;
    const int* p = idxg + ((size_t)b * 512 + 2 * (ty0 + r)) * 512 + 2 * (tx0 + c);
    // occupied iff any idx >= 0  <=>  AND of all four has sign bit clear
    float v = ((p[0] & p[1] & p[512] & p[513]) >= 0) ? 1.f : 0.f;
    m2[((size_t)b * 256 + ty0 + r) * 256 + tx0 + c] = v;
    sm2[r][c] = v;
  }
  __syncthreads();
  {
    int r = t >> 4, c = t & 15;
    float v = fmaxf(fmaxf(sm2[2 * r][2 * c], sm2[2 * r][2 * c + 1]),
                    fmaxf(sm2[2 * r + 1][2 * c], sm2[2 * r + 1][2 * c + 1]));
    m3[((size_t)b * 128 + (ty0 >> 1) + r) * 128 + (tx0 >> 1) + c] = v;
    sm3[r][c] = v;
  }
  __syncthreads();
  if (t < 64) {
    int r = t >> 3, c = t & 7;
    float v = fmaxf(fmaxf(sm3[2 * r][2 * c], sm3[2 * r][2 * c + 1]),
                    fmaxf(sm3[2 * r + 1][2 * c], sm3[2 * r + 1][2 * c + 1]));
    m4[((size_t)b * 64 + (ty0 >> 2) + r) * 64 + (tx0 >> 2) + c] = v;
  }
}

// ---- conv1 via MFMA: 5x5 s1 p2, 1 -> 32 ch, relu * m1, bf16 out ----
// GEMM: M=16 px, N=32 co (2 halves), K=25 taps pad 32. Input pre-split
// hi/lo bf16 (packed u32); D = Ah*Bh + Ah*Bl + Al*Bh.
// Block: 4 waves, wave w -> row R+w; 16 segments over a 256-px x-half.
__global__ __launch_bounds__(256) void k_conv1_mfma(
    const unsigned* __restrict__ grid2, const int* __restrict__ idxg,
    const unsigned short* __restrict__ pw1h,
    const unsigned short* __restrict__ pw1l,
    __hip_bfloat16* __restrict__ y1) {
  constexpr int PITCH = 264;
  __shared__ unsigned s_tile[8 * PITCH];  // 8.25 KB, hi|lo packed
  const int t = threadIdx.x;
  const int b = blockIdx.z, R = blockIdx.y * 4, x0 = blockIdx.x * 256;
  for (int i = t; i < 8 * 260; i += 256) {
    int rr = i / 260, cc = i - rr * 260;
    int gy = R - 2 + rr, gx = x0 - 2 + cc;
    unsigned v = 0;
    if (gy >= 0 && gy < G_ && gx >= 0 && gx < G_)
      v = grid2[((size_t)b * G_ + gy) * G_ + gx];
    s_tile[rr * PITCH + cc] = v;
  }

  const int lane = t & 63, w = t >> 6;
  const int r = lane & 15, g = lane >> 4;
  bf16x8 bh[2], bl[2];
#pragma unroll
  for (int h = 0; h < 2; h++) {
    bh[h] = *(const bf16x8*)&pw1h[(h * 64 + lane) * 8];
    bl[h] = *(const bf16x8*)&pw1l[(h * 64 + lane) * 8];
  }
  int toff[8]; bool tval[8];
#pragma unroll
  for (int j = 0; j < 8; j++) {
    int k = 8 * g + j;
    tval[j] = (k < 25);
    int kq = tval[j] ? k : 0;
    int ky = kq / 5, kx = kq - 5 * ky;
    toff[j] = (w + ky) * PITCH + kx;
  }
  __syncthreads();

  const int oy = R + w;
  const size_t rowo = ((size_t)b * G_ + oy) * G_;

  for (int s = 0; s < 16; s++) {
    const int oxl = s * 16;
    unsigned wv[8];
#pragma unroll
    for (int j = 0; j < 8; j++)
      wv[j] = tval[j] ? s_tile[toff[j] + oxl + r] : 0u;
    u32x4 ua, ul;
#pragma unroll
    for (int p = 0; p < 4; p++) {
      unsigned w0 = wv[2 * p], w1 = wv[2 * p + 1];
      ua[p] = (w0 & 0xffffu) | (w1 << 16);
      ul[p] = (w0 >> 16) | (w1 & 0xffff0000u);
    }
    bf16x8 ahv = __builtin_bit_cast(bf16x8, ua);
    bf16x8 alv = __builtin_bit_cast(bf16x8, ul);
    f32x4 acc0 = {0.f, 0.f, 0.f, 0.f}, acc1 = {0.f, 0.f, 0.f, 0.f};
    acc0 = __builtin_amdgcn_mfma_f32_16x16x32_bf16(ahv, bh[0], acc0, 0, 0, 0);
    acc1 = __builtin_amdgcn_mfma_f32_16x16x32_bf16(ahv, bh[1], acc1, 0, 0, 0);
    acc0 = __builtin_amdgcn_mfma_f32_16x16x32_bf16(ahv, bl[0], acc0, 0, 0, 0);
    acc1 = __builtin_amdgcn_mfma_f32_16x16x32_bf16(ahv, bl[1], acc1, 0, 0, 0);
    acc0 = __builtin_amdgcn_mfma_f32_16x16x32_bf16(alv, bh[0], acc0, 0, 0, 0);
    acc1 = __builtin_amdgcn_mfma_f32_16x16x32_bf16(alv, bh[1], acc1, 0, 0, 0);

#pragma unroll
    for (int q = 0; q < 4; q++) {
      const size_t opix = rowo + (x0 + oxl + g * 4 + q);
      const float m = (idxg[opix] >= 0) ? 1.f : 0.f;
      unsigned short* op = (unsigned short*)(y1 + opix * 32);
      op[r] = f2bf_bits(fmaxf(acc0[q], 0.f) * m);
      op[r + 16] = f2bf_bits(fmaxf(acc1[q], 0.f) * m);
    }
  }
}

// ---- conv 3x3 stride2 pad1, 32 -> 32 ch via MFMA implicit-GEMM ----
// NW waves/block; wave w -> output row oy = blockIdx.y*NW + w, NSEG 16-px
// segments. B-frags loaded directly from packed global table (no LDS).
template <int HI, int SEGS, int NW>
__global__ __launch_bounds__(NW * 64) void k_conv3x3s2_mfma(
    const __hip_bfloat16* __restrict__ in,
    const unsigned short* __restrict__ pw,
    const float* __restrict__ mask, __hip_bfloat16* __restrict__ out) {
  constexpr int WI = HI, HO = HI / 2, WO = WI / 2;
  constexpr int NSEG = WO / 16 / SEGS;
  const int t = threadIdx.x;
  const int lane = t & 63, w = t >> 6;
  const int r = lane & 15, g = lane >> 4;
  bf16x8 bw[9][2];
#pragma unroll
  for (int kk = 0; kk < 9; kk++)
#pragma unroll
    for (int h = 0; h < 2; h++)
      bw[kk][h] = *(const bf16x8*)&pw[((kk * 2 + h) * 64 + lane) * 8];

  const int b = blockIdx.z;
  const int oy = blockIdx.y * NW + w;
  const int ox_base = blockIdx.x * (WO / SEGS);
  const __hip_bfloat16* inb = in + (size_t)b * HI * WI * 32;

  for (int s = 0; s < NSEG; s++) {
    const int ox0 = ox_base + s * 16;
    f32x4 acc0 = {0.f, 0.f, 0.f, 0.f}, acc1 = {0.f, 0.f, 0.f, 0.f};
#pragma unroll
    for (int ky = 0; ky < 3; ky++) {
      const int iy = 2 * oy + ky - 1;  // in [-1, HI-1]
      const __hip_bfloat16* rowp = inb + (size_t)(iy < 0 ? 0 : iy) * WI * 32;
#pragma unroll
      for (int kx = 0; kx < 3; kx++) {
        const int ix = 2 * (ox0 + r) + kx - 1;  // in [-1, WI-1]
        uint4 v = *(const uint4*)(rowp + (size_t)(ix < 0 ? 0 : ix) * 32 + g * 8);
        if ((iy | ix) < 0) { v.x = 0; v.y = 0; v.z = 0; v.w = 0; }
        bf16x8 a = *reinterpret_cast<const bf16x8*>(&v);
        acc0 = __builtin_amdgcn_mfma_f32_16x16x32_bf16(a, bw[ky * 3 + kx][0],
                                                       acc0, 0, 0, 0);
        acc1 = __builtin_amdgcn_mfma_f32_16x16x32_bf16(a, bw[ky * 3 + kx][1],
                                                       acc1, 0, 0, 0);
      }
    }
    const size_t rowo = ((size_t)b * HO + oy) * WO;
#pragma unroll
    for (int q = 0; q < 4; q++) {
      const size_t opix = rowo + (ox0 + g * 4 + q);
      const float m = mask[opix];
      unsigned short* op = (unsigned short*)(out + opix * 32);
      op[r] = f2bf_bits(fmaxf(acc0[q], 0.f) * m);
      op[r + 16] = f2bf_bits(fmaxf(acc1[q], 0.f) * m);
    }
  }
}

// ---- masked mean pool over 64x64, per batch ----
__global__ __launch_bounds__(256) void k_pool(const __hip_bfloat16* __restrict__ y4,
                                              const float* __restrict__ m4,
                                              float* __restrict__ pooled) {
  const int b = blockIdx.x, t = threadIdx.x;
  const int c8 = t & 3, g = t >> 2;
  float s[8] = {0, 0, 0, 0, 0, 0, 0, 0};
  for (int p = g; p < 4096; p += 64) {
    uint4 raw = *(const uint4*)(y4 + ((size_t)b * 4096 + p) * 32 + c8 * 8);
#pragma unroll
    for (int cp = 0; cp < 4; cp++) {
      unsigned w = comp(raw, cp);
      s[2 * cp] += bf_lo(w);
      s[2 * cp + 1] += bf_hi(w);
    }
  }
  __shared__ float s_red[64][32];
  __shared__ float s_cnt[256];
#pragma unroll
  for (int j = 0; j < 8; j++) s_red[g][c8 * 8 + j] = s[j];
  float cnt = 0;
  for (int p = t; p < 4096; p += 256) cnt += m4[(size_t)b * 4096 + p];
  s_cnt[t] = cnt;
  __syncthreads();
  for (int st = 32; st > 0; st >>= 1) {
    if (g < st) {
#pragma unroll
      for (int j = 0; j < 8; j++) s_red[g][c8 * 8 + j] += s_red[g + st][c8 * 8 + j];
    }
    __syncthreads();
  }
  for (int st = 128; st > 0; st >>= 1) {
    if (t < st) s_cnt[t] += s_cnt[t + st];
    __syncthreads();
  }
  if (t < 32) pooled[b * 32 + t] = s_red[0][t] / fmaxf(s_cnt[0], 1.f);
}

// ---- final MLP ----
__global__ __launch_bounds__(256) void k_mlp(
    const float* __restrict__ pooled, const float* __restrict__ x2,
    const float* __restrict__ W1, const float* __restrict__ b1,
    const float* __restrict__ W2, const float* __restrict__ b2,
    const float* __restrict__ W3, const float* __restrict__ b3,
    float* __restrict__ outp) {
  __shared__ float s_h1[8 * 64];
  __shared__ float s_z[8 * 64];
  const int t = threadIdx.x;
  for (int i = t; i < 512; i += 256) {
    int bb = i >> 6, j = i & 63;
    float a = b1[j] + x2[bb * 3 + 0] * W1[0 * 64 + j] +
              x2[bb * 3 + 1] * W1[1 * 64 + j] + x2[bb * 3 + 2] * W1[2 * 64 + j];
    s_h1[i] = fmaxf(a, 0.f);
  }
  __syncthreads();
  {
    int bb = t >> 5, ci = t & 31;
    float a = b2[ci];
    for (int k = 0; k < 64; k++) a += s_h1[bb * 64 + k] * W2[k * 32 + ci];
    s_z[bb * 64 + 32 + ci] = a;                // h part (no relu per reference)
    s_z[bb * 64 + ci] = pooled[bb * 32 + ci];  // pooled part
  }
  __syncthreads();
  for (int o = t; o < 1024; o += 256) {
    int bb = o >> 7, j = o & 127;
    float a = b3[j];
    for (int k = 0; k < 64; k++) a += s_z[bb * 64 + k] * W3[k * 128 + j];
    outp[o] = fmaxf(a, 0.f);
  }
}

// ---------------------------------------------------------------------------
extern "C" void kernel_launch(void* const* d_in, const int* in_sizes, int n_in,
                              void* d_out, int out_size, void* d_ws,
                              size_t ws_size, hipStream_t stream) {
  const int* coords = (const int*)d_in[0];
  const float* feats = (const float*)d_in[1];
  const float* x2 = (const float*)d_in[2];
  const float* K1 = (const float*)d_in[3];
  const float* K2 = (const float*)d_in[4];
  const float* K3 = (const float*)d_in[5];
  const float* K4 = (const float*)d_in[6];
  const float* W1 = (const float*)d_in[7];
  const float* b1 = (const float*)d_in[8];
  const float* W2 = (const float*)d_in[9];
  const float* b2 = (const float*)d_in[10];
  const float* W3 = (const float*)d_in[11];
  const float* b3 = (const float*)d_in[12];
  float* outp = (float*)d_out;

  char* ws = (char*)d_ws;
  size_t off = 0;
  auto alloc = [&](size_t bytes) {
    char* p = ws + off;
    off += (bytes + 255) & ~(size_t)255;
    return p;
  };
  int* idxg = (int*)alloc(8ull * 512 * 512 * 4);
  unsigned* grid2 = (unsigned*)alloc(8ull * 512 * 512 * 4);
  __hip_bfloat16* y1 = (__hip_bfloat16*)alloc(8ull * 512 * 512 * 32 * 2);
  __hip_bfloat16* y2 = (__hip_bfloat16*)alloc(8ull * 256 * 256 * 32 * 2);
  __hip_bfloat16* y3 = (__hip_bfloat16*)alloc(8ull * 128 * 128 * 32 * 2);
  __hip_bfloat16* y4 = (__hip_bfloat16*)alloc(8ull * 64 * 64 * 32 * 2);
  float* m2 = (float*)alloc(8ull * 256 * 256 * 4);
  float* m3 = (float*)alloc(8ull * 128 * 128 * 4);
  float* m4 = (float*)alloc(8ull * 64 * 64 * 4);
  float* pooled = (float*)alloc(8 * 32 * 4);
  unsigned short* pw1h = (unsigned short*)alloc(128 * 8 * 2);
  unsigned short* pw1l = (unsigned short*)alloc(128 * 8 * 2);
  unsigned short* pw2 = (unsigned short*)alloc(1152 * 8 * 2);
  unsigned short* pw3 = (unsigned short*)alloc(1152 * 8 * 2);
  unsigned short* pw4 = (unsigned short*)alloc(1152 * 8 * 2);
  (void)ws_size; (void)in_sizes; (void)n_in; (void)out_size;

  hipMemsetAsync(idxg, 0xFF, 8ull * 512 * 512 * 4, stream);  // idx = -1

  k_packw<<<1, 256, 0, stream>>>(K1, K2, K3, K4, pw1h, pw1l, pw2, pw3, pw4);
  k_scatter<<<NPTS / 256, 256, 0, stream>>>(coords, idxg);
  k_grid<<<(8 * 512 * 512) / 256, 256, 0, stream>>>(idxg, feats, grid2);
  k_masks<<<dim3(8, 8, 8), 256, 0, stream>>>(idxg, m2, m3, m4);

  k_conv1_mfma<<<dim3(2, 128, 8), 256, 0, stream>>>(grid2, idxg, pw1h, pw1l, y1);

  k_conv3x3s2_mfma<512, 2, 4><<<dim3(2, 64, 8), 256, 0, stream>>>(y1, pw2, m2, y2);
  k_conv3x3s2_mfma<256, 2, 4><<<dim3(2, 32, 8), 256, 0, stream>>>(y2, pw3, m3, y3);
  k_conv3x3s2_mfma<128, 4, 1><<<dim3(4, 64, 8), 64, 0, stream>>>(y3, pw4, m4, y4);

  k_pool<<<8, 256, 0, stream>>>(y4, m4, pooled);
  k_mlp<<<1, 256, 0, stream>>>(pooled, x2, W1, b1, W2, b2, W3, b3, outp);
}

// Round 9
// 226.776 us; speedup vs baseline: 2.6884x; 1.0454x over previous
//
#include <hip/hip_runtime.h>
#include <hip/hip_bf16.h>
#include <stdint.h>

// ---------------------------------------------------------------------------
// SimplifiedSCNN on MI355X — round 9.
// vs round 8 (237 us; conv2 51 us latency-bound, HBM 27%, MfmaUtil 6.7%):
//  1. FUSED k_conv12: conv1(5x5 MFMA, hi/lo) -> y1 tile in LDS (XOR-swizzled
//     64B/px slots) -> conv2(3x3 s2 MFMA) -> y2. Eliminates the y1 HBM round
//     trip (134 MB W + 77 MB R) and conv2's global-load latency chain.
//  2. co-interleaved B-frag packing (co = 2*col + h): epilogues store u32
//     (co pairs) instead of 2x 2B — applied to conv12/conv3/conv4 + k_packw.
// Numerics bit-identical to round 8 (same op order) -> absmax 0.00390625.
// ---------------------------------------------------------------------------

static constexpr int G_ = 512;
static constexpr int NPTS = 8 * 32768;

#define DEVI __device__ __forceinline__

typedef __attribute__((ext_vector_type(8))) short bf16x8;
typedef __attribute__((ext_vector_type(4))) float f32x4;
typedef __attribute__((ext_vector_type(4))) unsigned u32x4;

DEVI float bf_lo(unsigned w) { return __uint_as_float(w << 16); }
DEVI float bf_hi(unsigned w) { return __uint_as_float(w & 0xFFFF0000u); }
DEVI unsigned comp(const uint4& v, int i) {
  return i == 0 ? v.x : i == 1 ? v.y : i == 2 ? v.z : v.w;
}
DEVI unsigned short f2bf_bits(float f) {   // round-to-nearest-even bf16
  unsigned u = __float_as_uint(f);
  unsigned r = u + 0x7FFFu + ((u >> 16) & 1u);
  return (unsigned short)(r >> 16);
}
DEVI unsigned pack2(float a, float b) {
  return (unsigned)f2bf_bits(a) | ((unsigned)f2bf_bits(b) << 16);
}

// ---- scatter: last point index wins per cell (matches sequential .set) ----
__global__ __launch_bounds__(256) void k_scatter(const int* __restrict__ coords,
                                                 int* __restrict__ idxg) {
  int i = blockIdx.x * 256 + threadIdx.x;
  if (i >= NPTS) return;
  int b = coords[3 * i], y = coords[3 * i + 1], x = coords[3 * i + 2];
  atomicMax(&idxg[((size_t)b * G_ + y) * G_ + x], i);
}

// ---- gather feats into grid, pre-split into (bf16_hi | bf16_lo<<16) ----
__global__ __launch_bounds__(256) void k_grid(const int* __restrict__ idxg,
                                              const float* __restrict__ feats,
                                              unsigned* __restrict__ grid2) {
  int i = blockIdx.x * 256 + threadIdx.x;
  int v = idxg[i];
  float f = (v >= 0) ? feats[v] : 0.0f;
  unsigned short hb = f2bf_bits(f);
  unsigned short lb = f2bf_bits(f - __uint_as_float((unsigned)hb << 16));
  grid2[i] = (unsigned)hb | ((unsigned)lb << 16);
}

// ---- one-time weight pack into B-frag tables (co-INTERLEAVED) ----
// Frag elem e=(kk*2+h)*64+lane, j -> k=8*(lane>>4)+j, co = 2*(lane&15) + h.
// => acc0 col r holds co 2r, acc1 col r holds co 2r+1 (u32-pair stores).
__global__ __launch_bounds__(256) void k_packw(
    const float* __restrict__ K1f, const float* __restrict__ K2,
    const float* __restrict__ K3, const float* __restrict__ K4,
    unsigned short* __restrict__ pw1h, unsigned short* __restrict__ pw1l,
    unsigned short* __restrict__ pw2, unsigned short* __restrict__ pw3,
    unsigned short* __restrict__ pw4) {
  const int t = threadIdx.x;
  if (t < 128) {  // K1: 25 taps padded to 32, hi/lo split
    int h = t >> 6, ln = t & 63;
    int g2 = ln >> 4, co = 2 * (ln & 15) + h;
#pragma unroll
    for (int j = 0; j < 8; j++) {
      int k = 8 * g2 + j;
      float v = (k < 25) ? K1f[k * 32 + co] : 0.f;
      unsigned short hb = f2bf_bits(v);
      pw1h[t * 8 + j] = hb;
      pw1l[t * 8 + j] = f2bf_bits(v - __uint_as_float((unsigned)hb << 16));
    }
  }
  const float* Ks[3] = {K2, K3, K4};
  unsigned short* ps[3] = {pw2, pw3, pw4};
  for (int m = 0; m < 3; m++)
    for (int e = t; e < 1152; e += 256) {
      int kk = e >> 7, rem = e & 127;
      int h = rem >> 6, ln = rem & 63;
      int g2 = ln >> 4, co = 2 * (ln & 15) + h;
#pragma unroll
      for (int j = 0; j < 8; j++)
        ps[m][e * 8 + j] = f2bf_bits(Ks[m][((kk * 32) + 8 * g2 + j) * 32 + co]);
    }
}

// ---- fused mask chain: m2 (from idxg) -> m3 -> m4 ----
__global__ __launch_bounds__(256) void k_masks(const int* __restrict__ idxg,
                                               float* __restrict__ m2,
                                               float* __restrict__ m3,
                                               float* __restrict__ m4) {
  __shared__ float sm2[32][32];
  __shared__ float sm3[16][16];
  const int b = blockIdx.z, ty0 = blockIdx.y * 32, tx0 = blockIdx.x * 32;
  const int t = threadIdx.x;
  for (int i = t; i < 1024; i += 256) {
    int r = i >> 5, c = i & 31;
    const int* p = idxg + ((size_t)b * 512 + 2 * (ty0 + r)) * 512 + 2 * (tx0 + c);
    float v = ((p[0] & p[1] & p[512] & p[513]) >= 0) ? 1.f : 0.f;
    m2[((size_t)b * 256 + ty0 + r) * 256 + tx0 + c] = v;
    sm2[r][c] = v;
  }
  __syncthreads();
  {
    int r = t >> 4, c = t & 15;
    float v = fmaxf(fmaxf(sm2[2 * r][2 * c], sm2[2 * r][2 * c + 1]),
                    fmaxf(sm2[2 * r + 1][2 * c], sm2[2 * r + 1][2 * c + 1]));
    m3[((size_t)b * 128 + (ty0 >> 1) + r) * 128 + (tx0 >> 1) + c] = v;
    sm3[r][c] = v;
  }
  __syncthreads();
  if (t < 64) {
    int r = t >> 3, c = t & 7;
    float v = fmaxf(fmaxf(sm3[2 * r][2 * c], sm3[2 * r][2 * c + 1]),
                    fmaxf(sm3[2 * r + 1][2 * c], sm3[2 * r + 1][2 * c + 1]));
    m4[((size_t)b * 64 + (ty0 >> 2) + r) * 64 + (tx0 >> 2) + c] = v;
  }
}

// ---- FUSED conv1(5x5 s1, hi/lo MFMA) + conv2(3x3 s2 MFMA) ----
// Block -> y2 tile 8x16 at (b, 8*by, 16*bx). Grid (16,32,8) = 4096 blocks.
// Needs: y1 tile 17x33 (computed into LDS, bf16, masked by m1),
//        grid tile 21x37 (staged, packed hi/lo u32), m1 tile 17x33.
// s_y1 layout: slot = iy*33+ix (64 B = 32 co bf16), XOR swizzle
//   byte = (slot*64 + off) ^ (((slot>>1)&7)<<4)
//   -> conv2 stride-2 b128 reads and conv1 b32 writes both ~2-way (free).
// conv1 segments: 34 row segs (17 rows x {0-15,16-31}) + 2 col segs for
// ix=32 (iy 0-15 and 1-16; overlap rows write identical values -> benign).
__global__ __launch_bounds__(256, 3) void k_conv12(
    const unsigned* __restrict__ grid2, const int* __restrict__ idxg,
    const unsigned short* __restrict__ pw1h,
    const unsigned short* __restrict__ pw1l,
    const unsigned short* __restrict__ pw2, const float* __restrict__ m2,
    __hip_bfloat16* __restrict__ y2) {
  __shared__ unsigned s_grid[21 * 40];           // 3,360 B
  __shared__ unsigned short s_m1[17 * 34];       // 1,156 B
  __shared__ unsigned short s_y1[17 * 33 * 32];  // 35,904 B

  const int t = threadIdx.x;
  const int b = blockIdx.z, by = blockIdx.y, bx = blockIdx.x;
  const int gyb = 16 * by - 3, gxb = 32 * bx - 3;  // s_grid origin
  const size_t ibase = (size_t)b * G_ * G_;

  // --- stage 1: grid tile + m1 tile ---
  for (int i = t; i < 21 * 37; i += 256) {
    int rr = i / 37, cc = i - rr * 37;
    int gy = gyb + rr, gx = gxb + cc;
    unsigned v = 0;
    if (gy >= 0 && gy < G_ && gx >= 0 && gx < G_)
      v = grid2[ibase + (size_t)gy * G_ + gx];
    s_grid[rr * 40 + cc] = v;
  }
  for (int i = t; i < 17 * 33; i += 256) {
    int rr = i / 33, cc = i - rr * 33;
    int gy = gyb + 2 + rr, gx = gxb + 2 + cc;  // y1 local (rr,cc) origin
    unsigned short mv = 0;
    if (gy >= 0 && gy < G_ && gx >= 0 && gx < G_)
      mv = (idxg[ibase + (size_t)gy * G_ + gx] >= 0) ? 1 : 0;
    s_m1[rr * 34 + cc] = mv;
  }

  const int lane = t & 63, w = t >> 6;
  const int r = lane & 15, g = lane >> 4;

  bf16x8 b1h[2], b1l[2];
#pragma unroll
  for (int h = 0; h < 2; h++) {
    b1h[h] = *(const bf16x8*)&pw1h[(h * 64 + lane) * 8];
    b1l[h] = *(const bf16x8*)&pw1l[(h * 64 + lane) * 8];
  }
  bf16x8 bw2[9][2];
#pragma unroll
  for (int kk = 0; kk < 9; kk++)
#pragma unroll
    for (int h = 0; h < 2; h++)
      bw2[kk][h] = *(const bf16x8*)&pw2[((kk * 2 + h) * 64 + lane) * 8];

  int reloff[8]; bool tval[8];
#pragma unroll
  for (int j = 0; j < 8; j++) {
    int k = 8 * g + j;
    tval[j] = (k < 25);
    int kq = tval[j] ? k : 0;
    reloff[j] = (kq / 5) * 40 + (kq % 5);
  }

  __syncthreads();

  // --- conv1 stage: 36 segments, wave-strided ---
  for (int seg = w; seg < 36; seg += 4) {
    int piy, pix;
    if (seg < 34) { piy = seg >> 1; pix = ((seg & 1) << 4) + r; }
    else          { piy = (seg - 34) + r; pix = 32; }
    const int tapb = piy * 40 + pix;
    unsigned wv[8];
#pragma unroll
    for (int j = 0; j < 8; j++)
      wv[j] = tval[j] ? s_grid[tapb + reloff[j]] : 0u;
    u32x4 ua, ul;
#pragma unroll
    for (int p = 0; p < 4; p++) {
      unsigned w0 = wv[2 * p], w1 = wv[2 * p + 1];
      ua[p] = (w0 & 0xffffu) | (w1 << 16);
      ul[p] = (w0 >> 16) | (w1 & 0xffff0000u);
    }
    bf16x8 ahv = __builtin_bit_cast(bf16x8, ua);
    bf16x8 alv = __builtin_bit_cast(bf16x8, ul);
    f32x4 acc0 = {0.f, 0.f, 0.f, 0.f}, acc1 = {0.f, 0.f, 0.f, 0.f};
    acc0 = __builtin_amdgcn_mfma_f32_16x16x32_bf16(ahv, b1h[0], acc0, 0, 0, 0);
    acc1 = __builtin_amdgcn_mfma_f32_16x16x32_bf16(ahv, b1h[1], acc1, 0, 0, 0);
    acc0 = __builtin_amdgcn_mfma_f32_16x16x32_bf16(ahv, b1l[0], acc0, 0, 0, 0);
    acc1 = __builtin_amdgcn_mfma_f32_16x16x32_bf16(ahv, b1l[1], acc1, 0, 0, 0);
    acc0 = __builtin_amdgcn_mfma_f32_16x16x32_bf16(alv, b1h[0], acc0, 0, 0, 0);
    acc1 = __builtin_amdgcn_mfma_f32_16x16x32_bf16(alv, b1h[1], acc1, 0, 0, 0);
#pragma unroll
    for (int q = 0; q < 4; q++) {
      const int m = g * 4 + q;
      int eiy, eix;
      if (seg < 34) { eiy = seg >> 1; eix = ((seg & 1) << 4) + m; }
      else          { eiy = (seg - 34) + m; eix = 32; }
      float mk = (float)s_m1[eiy * 34 + eix];
      unsigned ov = pack2(fmaxf(acc0[q], 0.f) * mk, fmaxf(acc1[q], 0.f) * mk);
      int slot = eiy * 33 + eix;
      unsigned byo = (unsigned)(slot * 64 + 4 * r) ^
                     ((((unsigned)slot >> 1) & 7u) << 4);
      *(unsigned*)((char*)s_y1 + byo) = ov;
    }
  }
  __syncthreads();

  // --- conv2 stage: 8 output rows, wave-strided ---
  const int ty0 = 8 * by, tx0 = 16 * bx;
  for (int oy = w; oy < 8; oy += 4) {
    f32x4 acc0 = {0.f, 0.f, 0.f, 0.f}, acc1 = {0.f, 0.f, 0.f, 0.f};
#pragma unroll
    for (int ky = 0; ky < 3; ky++) {
      const int iy = 2 * oy + ky;  // 0..16
#pragma unroll
      for (int kx = 0; kx < 3; kx++) {
        const int slot = iy * 33 + 2 * r + kx;  // ix 0..32
        unsigned byo = (unsigned)(slot * 64 + g * 16) ^
                       ((((unsigned)slot >> 1) & 7u) << 4);
        bf16x8 a = *(const bf16x8*)((char*)s_y1 + byo);
        acc0 = __builtin_amdgcn_mfma_f32_16x16x32_bf16(a, bw2[ky * 3 + kx][0],
                                                       acc0, 0, 0, 0);
        acc1 = __builtin_amdgcn_mfma_f32_16x16x32_bf16(a, bw2[ky * 3 + kx][1],
                                                       acc1, 0, 0, 0);
      }
    }
    const size_t rowo = ((size_t)b * 256 + ty0 + oy) * 256;
#pragma unroll
    for (int q = 0; q < 4; q++) {
      const int m = g * 4 + q;
      const size_t opix = rowo + tx0 + m;
      const float mk = m2[opix];
      unsigned ov = pack2(fmaxf(acc0[q], 0.f) * mk, fmaxf(acc1[q], 0.f) * mk);
      *(unsigned*)(y2 + opix * 32 + 2 * r) = ov;
    }
  }
}

// ---- conv 3x3 stride2 pad1, 32 -> 32 ch via MFMA implicit-GEMM ----
// (interleaved pw -> u32-pair stores in epilogue)
template <int HI, int SEGS, int NW>
__global__ __launch_bounds__(NW * 64) void k_conv3x3s2_mfma(
    const __hip_bfloat16* __restrict__ in,
    const unsigned short* __restrict__ pw,
    const float* __restrict__ mask, __hip_bfloat16* __restrict__ out) {
  constexpr int WI = HI, HO = HI / 2, WO = WI / 2;
  constexpr int NSEG = WO / 16 / SEGS;
  const int t = threadIdx.x;
  const int lane = t & 63, w = t >> 6;
  const int r = lane & 15, g = lane >> 4;
  bf16x8 bw[9][2];
#pragma unroll
  for (int kk = 0; kk < 9; kk++)
#pragma unroll
    for (int h = 0; h < 2; h++)
      bw[kk][h] = *(const bf16x8*)&pw[((kk * 2 + h) * 64 + lane) * 8];

  const int b = blockIdx.z;
  const int oy = blockIdx.y * NW + w;
  const int ox_base = blockIdx.x * (WO / SEGS);
  const __hip_bfloat16* inb = in + (size_t)b * HI * WI * 32;

  for (int s = 0; s < NSEG; s++) {
    const int ox0 = ox_base + s * 16;
    f32x4 acc0 = {0.f, 0.f, 0.f, 0.f}, acc1 = {0.f, 0.f, 0.f, 0.f};
#pragma unroll
    for (int ky = 0; ky < 3; ky++) {
      const int iy = 2 * oy + ky - 1;  // in [-1, HI-1]
      const __hip_bfloat16* rowp = inb + (size_t)(iy < 0 ? 0 : iy) * WI * 32;
#pragma unroll
      for (int kx = 0; kx < 3; kx++) {
        const int ix = 2 * (ox0 + r) + kx - 1;  // in [-1, WI-1]
        uint4 v = *(const uint4*)(rowp + (size_t)(ix < 0 ? 0 : ix) * 32 + g * 8);
        if ((iy | ix) < 0) { v.x = 0; v.y = 0; v.z = 0; v.w = 0; }
        bf16x8 a = *reinterpret_cast<const bf16x8*>(&v);
        acc0 = __builtin_amdgcn_mfma_f32_16x16x32_bf16(a, bw[ky * 3 + kx][0],
                                                       acc0, 0, 0, 0);
        acc1 = __builtin_amdgcn_mfma_f32_16x16x32_bf16(a, bw[ky * 3 + kx][1],
                                                       acc1, 0, 0, 0);
      }
    }
    const size_t rowo = ((size_t)b * HO + oy) * WO;
#pragma unroll
    for (int q = 0; q < 4; q++) {
      const size_t opix = rowo + (ox0 + g * 4 + q);
      const float m = mask[opix];
      unsigned ov = pack2(fmaxf(acc0[q], 0.f) * m, fmaxf(acc1[q], 0.f) * m);
      *(unsigned*)(out + opix * 32 + 2 * r) = ov;
    }
  }
}

// ---- masked mean pool over 64x64, per batch ----
__global__ __launch_bounds__(256) void k_pool(const __hip_bfloat16* __restrict__ y4,
                                              const float* __restrict__ m4,
                                              float* __restrict__ pooled) {
  const int b = blockIdx.x, t = threadIdx.x;
  const int c8 = t & 3, g = t >> 2;
  float s[8] = {0, 0, 0, 0, 0, 0, 0, 0};
  for (int p = g; p < 4096; p += 64) {
    uint4 raw = *(const uint4*)(y4 + ((size_t)b * 4096 + p) * 32 + c8 * 8);
#pragma unroll
    for (int cp = 0; cp < 4; cp++) {
      unsigned w = comp(raw, cp);
      s[2 * cp] += bf_lo(w);
      s[2 * cp + 1] += bf_hi(w);
    }
  }
  __shared__ float s_red[64][32];
  __shared__ float s_cnt[256];
#pragma unroll
  for (int j = 0; j < 8; j++) s_red[g][c8 * 8 + j] = s[j];
  float cnt = 0;
  for (int p = t; p < 4096; p += 256) cnt += m4[(size_t)b * 4096 + p];
  s_cnt[t] = cnt;
  __syncthreads();
  for (int st = 32; st > 0; st >>= 1) {
    if (g < st) {
#pragma unroll
      for (int j = 0; j < 8; j++) s_red[g][c8 * 8 + j] += s_red[g + st][c8 * 8 + j];
    }
    __syncthreads();
  }
  for (int st = 128; st > 0; st >>= 1) {
    if (t < st) s_cnt[t] += s_cnt[t + st];
    __syncthreads();
  }
  if (t < 32) pooled[b * 32 + t] = s_red[0][t] / fmaxf(s_cnt[0], 1.f);
}

// ---- final MLP ----
__global__ __launch_bounds__(256) void k_mlp(
    const float* __restrict__ pooled, const float* __restrict__ x2,
    const float* __restrict__ W1, const float* __restrict__ b1,
    const float* __restrict__ W2, const float* __restrict__ b2,
    const float* __restrict__ W3, const float* __restrict__ b3,
    float* __restrict__ outp) {
  __shared__ float s_h1[8 * 64];
  __shared__ float s_z[8 * 64];
  const int t = threadIdx.x;
  for (int i = t; i < 512; i += 256) {
    int bb = i >> 6, j = i & 63;
    float a = b1[j] + x2[bb * 3 + 0] * W1[0 * 64 + j] +
              x2[bb * 3 + 1] * W1[1 * 64 + j] + x2[bb * 3 + 2] * W1[2 * 64 + j];
    s_h1[i] = fmaxf(a, 0.f);
  }
  __syncthreads();
  {
    int bb = t >> 5, ci = t & 31;
    float a = b2[ci];
    for (int k = 0; k < 64; k++) a += s_h1[bb * 64 + k] * W2[k * 32 + ci];
    s_z[bb * 64 + 32 + ci] = a;                // h part (no relu per reference)
    s_z[bb * 64 + ci] = pooled[bb * 32 + ci];  // pooled part
  }
  __syncthreads();
  for (int o = t; o < 1024; o += 256) {
    int bb = o >> 7, j = o & 127;
    float a = b3[j];
    for (int k = 0; k < 64; k++) a += s_z[bb * 64 + k] * W3[k * 128 + j];
    outp[o] = fmaxf(a, 0.f);
  }
}

// ---------------------------------------------------------------------------
extern "C" void kernel_launch(void* const* d_in, const int* in_sizes, int n_in,
                              void* d_out, int out_size, void* d_ws,
                              size_t ws_size, hipStream_t stream) {
  const int* coords = (const int*)d_in[0];
  const float* feats = (const float*)d_in[1];
  const float* x2 = (const float*)d_in[2];
  const float* K1 = (const float*)d_in[3];
  const float* K2 = (const float*)d_in[4];
  const float* K3 = (const float*)d_in[5];
  const float* K4 = (const float*)d_in[6];
  const float* W1 = (const float*)d_in[7];
  const float* b1 = (const float*)d_in[8];
  const float* W2 = (const float*)d_in[9];
  const float* b2 = (const float*)d_in[10];
  const float* W3 = (const float*)d_in[11];
  const float* b3 = (const float*)d_in[12];
  float* outp = (float*)d_out;

  char* ws = (char*)d_ws;
  size_t off = 0;
  auto alloc = [&](size_t bytes) {
    char* p = ws + off;
    off += (bytes + 255) & ~(size_t)255;
    return p;
  };
  int* idxg = (int*)alloc(8ull * 512 * 512 * 4);
  unsigned* grid2 = (unsigned*)alloc(8ull * 512 * 512 * 4);
  __hip_bfloat16* y2 = (__hip_bfloat16*)alloc(8ull * 256 * 256 * 32 * 2);
  __hip_bfloat16* y3 = (__hip_bfloat16*)alloc(8ull * 128 * 128 * 32 * 2);
  __hip_bfloat16* y4 = (__hip_bfloat16*)alloc(8ull * 64 * 64 * 32 * 2);
  float* m2 = (float*)alloc(8ull * 256 * 256 * 4);
  float* m3 = (float*)alloc(8ull * 128 * 128 * 4);
  float* m4 = (float*)alloc(8ull * 64 * 64 * 4);
  float* pooled = (float*)alloc(8 * 32 * 4);
  unsigned short* pw1h = (unsigned short*)alloc(128 * 8 * 2);
  unsigned short* pw1l = (unsigned short*)alloc(128 * 8 * 2);
  unsigned short* pw2 = (unsigned short*)alloc(1152 * 8 * 2);
  unsigned short* pw3 = (unsigned short*)alloc(1152 * 8 * 2);
  unsigned short* pw4 = (unsigned short*)alloc(1152 * 8 * 2);
  (void)ws_size; (void)in_sizes; (void)n_in; (void)out_size;

  hipMemsetAsync(idxg, 0xFF, 8ull * 512 * 512 * 4, stream);  // idx = -1

  k_packw<<<1, 256, 0, stream>>>(K1, K2, K3, K4, pw1h, pw1l, pw2, pw3, pw4);
  k_scatter<<<NPTS / 256, 256, 0, stream>>>(coords, idxg);
  k_grid<<<(8 * 512 * 512) / 256, 256, 0, stream>>>(idxg, feats, grid2);
  k_masks<<<dim3(8, 8, 8), 256, 0, stream>>>(idxg, m2, m3, m4);

  // fused conv1+conv2: y2 tile 8x16 per block
  k_conv12<<<dim3(16, 32, 8), 256, 0, stream>>>(grid2, idxg, pw1h, pw1l, pw2,
                                                m2, y2);

  k_conv3x3s2_mfma<256, 2, 4><<<dim3(2, 32, 8), 256, 0, stream>>>(y2, pw3, m3, y3);
  k_conv3x3s2_mfma<128, 4, 1><<<dim3(4, 64, 8), 64, 0, stream>>>(y3, pw4, m4, y4);

  k_pool<<<8, 256, 0, stream>>>(y4, m4, pooled);
  k_mlp<<<1, 256, 0, stream>>>(pooled, x2, W1, b1, W2, b2, W3, b3, outp);
}

// Round 11
// 206.924 us; speedup vs baseline: 2.9463x; 1.0959x over previous
//
#include <hip/hip_runtime.h>
#include <hip/hip_bf16.h>
#include <stdint.h>

// ---------------------------------------------------------------------------
// SimplifiedSCNN on MI355X — round 11 (round 10 + compile fix).
// vs round 9 (227 us; conv12 70.4 us VALU-bound: VALUBusy 66%, MfmaUtil 13%):
//  1. OPERAND SWAP in all convs: D = W*P (weights = A operand, pixels = B).
//     A/B frags share the same lane layout on 16x16x32, so input reads are
//     unchanged; C-layout becomes col=pixel, rows=co. With a row-permuted
//     weight pack (co = 8*(m>>2)+(m&3)+4h), each lane owns ONE pixel x co
//     8g..8g+7 -> epilogue = 1 b128 store + 1 mask read (was 4 scattered
//     stores + 4 mask reads + 4 addr swizzles).
//  2. bf16 pack via integer RNE (f2bf_bits — validated bit-exact r5-r9;
//     __hip_bfloat162 bit_cast does NOT compile on this ROCm).
//  3. hi/lo repack via v_perm_b32 (__builtin_amdgcn_perm).
//  4. conv3 re-gridded: 2048 blocks x 128 thr (was 512x256, latency-bound).
//  5. k_packw folded into k_masks (block 0) -> one fewer dispatch.
// FP summation order per output preserved -> absmax stays 0.00390625.
// ---------------------------------------------------------------------------

static constexpr int G_ = 512;
static constexpr int NPTS = 8 * 32768;

#define DEVI __device__ __forceinline__

typedef __attribute__((ext_vector_type(8))) short bf16x8;
typedef __attribute__((ext_vector_type(4))) float f32x4;

DEVI float bf_lo(unsigned w) { return __uint_as_float(w << 16); }
DEVI float bf_hi(unsigned w) { return __uint_as_float(w & 0xFFFF0000u); }
DEVI unsigned comp(const uint4& v, int i) {
  return i == 0 ? v.x : i == 1 ? v.y : i == 2 ? v.z : v.w;
}
DEVI unsigned short f2bf_bits(float f) {   // round-to-nearest-even bf16
  unsigned u = __float_as_uint(f);
  unsigned r = u + 0x7FFFu + ((u >> 16) & 1u);
  return (unsigned short)(r >> 16);
}
DEVI unsigned pkbf(float a, float b) {     // packed bf16 pair (integer RNE)
  return (unsigned)f2bf_bits(a) | ((unsigned)f2bf_bits(b) << 16);
}
// relu + pack 8 accumulator values (co 8g..8g+7) + AND-mask
DEVI uint4 quad_pack(const f32x4& a0, const f32x4& a1, unsigned msk) {
  uint4 o;
  o.x = pkbf(fmaxf(a0[0], 0.f), fmaxf(a0[1], 0.f)) & msk;
  o.y = pkbf(fmaxf(a0[2], 0.f), fmaxf(a0[3], 0.f)) & msk;
  o.z = pkbf(fmaxf(a1[0], 0.f), fmaxf(a1[1], 0.f)) & msk;
  o.w = pkbf(fmaxf(a1[2], 0.f), fmaxf(a1[3], 0.f)) & msk;
  return o;
}

// ---- scatter: last point index wins per cell (matches sequential .set) ----
__global__ __launch_bounds__(256) void k_scatter(const int* __restrict__ coords,
                                                 int* __restrict__ idxg) {
  int i = blockIdx.x * 256 + threadIdx.x;
  if (i >= NPTS) return;
  int b = coords[3 * i], y = coords[3 * i + 1], x = coords[3 * i + 2];
  atomicMax(&idxg[((size_t)b * G_ + y) * G_ + x], i);
}

// ---- gather feats into grid, pre-split into (bf16_hi | bf16_lo<<16) ----
__global__ __launch_bounds__(256) void k_grid(const int* __restrict__ idxg,
                                              const float* __restrict__ feats,
                                              unsigned* __restrict__ grid2) {
  int i = blockIdx.x * 256 + threadIdx.x;
  int v = idxg[i];
  float f = (v >= 0) ? feats[v] : 0.0f;
  unsigned short hb = f2bf_bits(f);
  unsigned short lb = f2bf_bits(f - __uint_as_float((unsigned)hb << 16));
  grid2[i] = (unsigned)hb | ((unsigned)lb << 16);
}

// ---- fused mask chain + (block 0) weight pack ----
// Weight A-frag layout: half h, lane: rows m=lane&15 -> co=8*(m>>2)+(m&3)+4h,
// k = 8*(lane>>4)+j. Gives lane (col, g) co 8g..8g+3 in acc0, 8g+4..7 in acc1.
__global__ __launch_bounds__(256) void k_masks(
    const int* __restrict__ idxg, float* __restrict__ m2,
    float* __restrict__ m3, float* __restrict__ m4,
    const float* __restrict__ K1f, const float* __restrict__ K2,
    const float* __restrict__ K3, const float* __restrict__ K4,
    unsigned short* __restrict__ pw1h, unsigned short* __restrict__ pw1l,
    unsigned short* __restrict__ pw2, unsigned short* __restrict__ pw3,
    unsigned short* __restrict__ pw4) {
  __shared__ float sm2[32][32];
  __shared__ float sm3[16][16];
  const int b = blockIdx.z, ty0 = blockIdx.y * 32, tx0 = blockIdx.x * 32;
  const int t = threadIdx.x;

  if (blockIdx.x == 0 && blockIdx.y == 0 && blockIdx.z == 0) {
    if (t < 128) {  // K1: 25 taps padded to 32, hi/lo split
      int h = t >> 6, ln = t & 63;
      int m = ln & 15, g2 = ln >> 4;
      int co = 8 * (m >> 2) + (m & 3) + 4 * h;
#pragma unroll
      for (int j = 0; j < 8; j++) {
        int k = 8 * g2 + j;
        float v = (k < 25) ? K1f[k * 32 + co] : 0.f;
        unsigned short hb = f2bf_bits(v);
        pw1h[t * 8 + j] = hb;
        pw1l[t * 8 + j] = f2bf_bits(v - __uint_as_float((unsigned)hb << 16));
      }
    }
    const float* Ks[3] = {K2, K3, K4};
    unsigned short* ps[3] = {pw2, pw3, pw4};
    for (int m_ = 0; m_ < 3; m_++)
      for (int e = t; e < 1152; e += 256) {
        int kk = e >> 7, rem = e & 127;
        int h = rem >> 6, ln = rem & 63;
        int m = ln & 15, g2 = ln >> 4;
        int co = 8 * (m >> 2) + (m & 3) + 4 * h;
#pragma unroll
        for (int j = 0; j < 8; j++)
          ps[m_][e * 8 + j] =
              f2bf_bits(Ks[m_][((kk * 32) + 8 * g2 + j) * 32 + co]);
      }
  }

  for (int i = t; i < 1024; i += 256) {
    int r = i >> 5, c = i & 31;
    const int* p = idxg + ((size_t)b * 512 + 2 * (ty0 + r)) * 512 + 2 * (tx0 + c);
    float v = ((p[0] & p[1] & p[512] & p[513]) >= 0) ? 1.f : 0.f;
    m2[((size_t)b * 256 + ty0 + r) * 256 + tx0 + c] = v;
    sm2[r][c] = v;
  }
  __syncthreads();
  {
    int r = t >> 4, c = t & 15;
    float v = fmaxf(fmaxf(sm2[2 * r][2 * c], sm2[2 * r][2 * c + 1]),
                    fmaxf(sm2[2 * r + 1][2 * c], sm2[2 * r + 1][2 * c + 1]));
    m3[((size_t)b * 128 + (ty0 >> 1) + r) * 128 + (tx0 >> 1) + c] = v;
    sm3[r][c] = v;
  }
  __syncthreads();
  if (t < 64) {
    int r = t >> 3, c = t & 7;
    float v = fmaxf(fmaxf(sm3[2 * r][2 * c], sm3[2 * r][2 * c + 1]),
                    fmaxf(sm3[2 * r + 1][2 * c], sm3[2 * r + 1][2 * c + 1]));
    m4[((size_t)b * 64 + (ty0 >> 2) + r) * 64 + (tx0 >> 2) + c] = v;
  }
}

// ---- FUSED conv1(5x5 s1, hi/lo MFMA) + conv2(3x3 s2 MFMA), D = W*P ----
// Block -> y2 tile 8x16 at (b, 8*by, 16*bx). Grid (16,32,8) = 4096 blocks.
// s_y1 slot = iy*33+ix (64 B = 32 co bf16), swizzle byte ^= ((slot>>1)&7)<<4.
// conv1 epilogue: lane owns pixel col r, co 8g..8g+7 -> ONE ds_write_b128.
// conv2 reads slot bytes g*16 (unchanged); epilogue ONE global dwordx4.
__global__ __launch_bounds__(256, 3) void k_conv12(
    const unsigned* __restrict__ grid2, const int* __restrict__ idxg,
    const unsigned short* __restrict__ pw1h,
    const unsigned short* __restrict__ pw1l,
    const unsigned short* __restrict__ pw2, const float* __restrict__ m2,
    __hip_bfloat16* __restrict__ y2) {
  __shared__ unsigned s_grid[21 * 40];           // 3,360 B
  __shared__ unsigned short s_m1[17 * 34];       // 1,156 B
  __shared__ unsigned short s_y1[17 * 33 * 32];  // 35,904 B

  const int t = threadIdx.x;
  const int b = blockIdx.z, by = blockIdx.y, bx = blockIdx.x;
  const int gyb = 16 * by - 3, gxb = 32 * bx - 3;  // s_grid origin
  const size_t ibase = (size_t)b * G_ * G_;

  // --- stage: grid tile + m1 tile ---
  for (int i = t; i < 21 * 37; i += 256) {
    int rr = i / 37, cc = i - rr * 37;
    int gy = gyb + rr, gx = gxb + cc;
    unsigned v = 0;
    if (gy >= 0 && gy < G_ && gx >= 0 && gx < G_)
      v = grid2[ibase + (size_t)gy * G_ + gx];
    s_grid[rr * 40 + cc] = v;
  }
  for (int i = t; i < 17 * 33; i += 256) {
    int rr = i / 33, cc = i - rr * 33;
    int gy = gyb + 2 + rr, gx = gxb + 2 + cc;
    unsigned short mv = 0;
    if (gy >= 0 && gy < G_ && gx >= 0 && gx < G_)
      mv = (idxg[ibase + (size_t)gy * G_ + gx] >= 0) ? 1 : 0;
    s_m1[rr * 34 + cc] = mv;
  }

  const int lane = t & 63, w = t >> 6;
  const int r = lane & 15, g = lane >> 4;

  bf16x8 b1h[2], b1l[2];
#pragma unroll
  for (int h = 0; h < 2; h++) {
    b1h[h] = *(const bf16x8*)&pw1h[(h * 64 + lane) * 8];
    b1l[h] = *(const bf16x8*)&pw1l[(h * 64 + lane) * 8];
  }

  int reloff[8]; bool tval[8];
#pragma unroll
  for (int j = 0; j < 8; j++) {
    int k = 8 * g + j;
    tval[j] = (k < 25);
    int kq = tval[j] ? k : 0;
    reloff[j] = (kq / 5) * 40 + (kq % 5);
  }

  __syncthreads();

  // --- conv1 stage: 36 segments, wave-strided ---
  for (int seg = w; seg < 36; seg += 4) {
    int eiy, eix;
    if (seg < 34) { eiy = seg >> 1; eix = ((seg & 1) << 4) + r; }
    else          { eiy = (seg - 34) + r; eix = 32; }
    const int tapb = eiy * 40 + eix;
    unsigned wv[8];
#pragma unroll
    for (int j = 0; j < 8; j++)
      wv[j] = tval[j] ? s_grid[tapb + reloff[j]] : 0u;
    // hi/lo repack via v_perm_b32
    uint4 ua, ul;
#pragma unroll
    for (int p = 0; p < 4; p++) {
      unsigned lo = __builtin_amdgcn_perm(wv[2 * p + 1], wv[2 * p], 0x05040100u);
      unsigned hi = __builtin_amdgcn_perm(wv[2 * p + 1], wv[2 * p], 0x07060302u);
      if (p == 0) { ua.x = lo; ul.x = hi; }
      else if (p == 1) { ua.y = lo; ul.y = hi; }
      else if (p == 2) { ua.z = lo; ul.z = hi; }
      else { ua.w = lo; ul.w = hi; }
    }
    bf16x8 ph = __builtin_bit_cast(bf16x8, ua);
    bf16x8 pl = __builtin_bit_cast(bf16x8, ul);
    f32x4 acc0 = {0.f, 0.f, 0.f, 0.f}, acc1 = {0.f, 0.f, 0.f, 0.f};
    acc0 = __builtin_amdgcn_mfma_f32_16x16x32_bf16(b1h[0], ph, acc0, 0, 0, 0);
    acc1 = __builtin_amdgcn_mfma_f32_16x16x32_bf16(b1h[1], ph, acc1, 0, 0, 0);
    acc0 = __builtin_amdgcn_mfma_f32_16x16x32_bf16(b1l[0], ph, acc0, 0, 0, 0);
    acc1 = __builtin_amdgcn_mfma_f32_16x16x32_bf16(b1l[1], ph, acc1, 0, 0, 0);
    acc0 = __builtin_amdgcn_mfma_f32_16x16x32_bf16(b1h[0], pl, acc0, 0, 0, 0);
    acc1 = __builtin_amdgcn_mfma_f32_16x16x32_bf16(b1h[1], pl, acc1, 0, 0, 0);

    unsigned msk = s_m1[eiy * 34 + eix] ? 0xFFFFFFFFu : 0u;
    uint4 o = quad_pack(acc0, acc1, msk);
    int slot = eiy * 33 + eix;
    unsigned byo = (unsigned)(slot * 64 + 16 * g) ^
                   ((((unsigned)slot >> 1) & 7u) << 4);
    *(uint4*)((char*)s_y1 + byo) = o;
  }

  bf16x8 bw2[9][2];
#pragma unroll
  for (int kk = 0; kk < 9; kk++)
#pragma unroll
    for (int h = 0; h < 2; h++)
      bw2[kk][h] = *(const bf16x8*)&pw2[((kk * 2 + h) * 64 + lane) * 8];

  __syncthreads();

  // --- conv2 stage: 8 output rows, wave-strided ---
  const int ty0 = 8 * by, tx0 = 16 * bx;
  const unsigned* m2u = (const unsigned*)m2;
  for (int oy = w; oy < 8; oy += 4) {
    f32x4 acc0 = {0.f, 0.f, 0.f, 0.f}, acc1 = {0.f, 0.f, 0.f, 0.f};
#pragma unroll
    for (int ky = 0; ky < 3; ky++) {
      const int iy = 2 * oy + ky;  // 0..16
#pragma unroll
      for (int kx = 0; kx < 3; kx++) {
        const int slot = iy * 33 + 2 * r + kx;  // ix 0..32
        unsigned byo = (unsigned)(slot * 64 + g * 16) ^
                       ((((unsigned)slot >> 1) & 7u) << 4);
        bf16x8 a = *(const bf16x8*)((char*)s_y1 + byo);
        acc0 = __builtin_amdgcn_mfma_f32_16x16x32_bf16(bw2[ky * 3 + kx][0], a,
                                                       acc0, 0, 0, 0);
        acc1 = __builtin_amdgcn_mfma_f32_16x16x32_bf16(bw2[ky * 3 + kx][1], a,
                                                       acc1, 0, 0, 0);
      }
    }
    const size_t opix = ((size_t)b * 256 + ty0 + oy) * 256 + tx0 + r;
    unsigned msk = m2u[opix] ? 0xFFFFFFFFu : 0u;
    uint4 o = quad_pack(acc0, acc1, msk);
    *(uint4*)(y2 + opix * 32 + 8 * g) = o;
  }
}

// ---- conv 3x3 stride2 pad1, 32 -> 32 ch via MFMA implicit-GEMM, D = W*P ----
// NW waves/block; wave w -> output row oy = blockIdx.y*NW + w, NSEG 16-px
// segments. Input reads unchanged; epilogue: lane owns pixel ox0+r, co
// 8g..8g+7 -> one dwordx4 store + one mask read.
template <int HI, int SEGS, int NW>
__global__ __launch_bounds__(NW * 64) void k_conv3x3s2_mfma(
    const __hip_bfloat16* __restrict__ in,
    const unsigned short* __restrict__ pw,
    const float* __restrict__ mask, __hip_bfloat16* __restrict__ out) {
  constexpr int WI = HI, HO = HI / 2, WO = WI / 2;
  constexpr int NSEG = WO / 16 / SEGS;
  const int t = threadIdx.x;
  const int lane = t & 63, w = t >> 6;
  const int r = lane & 15, g = lane >> 4;
  bf16x8 bw[9][2];
#pragma unroll
  for (int kk = 0; kk < 9; kk++)
#pragma unroll
    for (int h = 0; h < 2; h++)
      bw[kk][h] = *(const bf16x8*)&pw[((kk * 2 + h) * 64 + lane) * 8];

  const int b = blockIdx.z;
  const int oy = blockIdx.y * NW + w;
  const int ox_base = blockIdx.x * (WO / SEGS);
  const __hip_bfloat16* inb = in + (size_t)b * HI * WI * 32;
  const unsigned* masku = (const unsigned*)mask;

  for (int s = 0; s < NSEG; s++) {
    const int ox0 = ox_base + s * 16;
    f32x4 acc0 = {0.f, 0.f, 0.f, 0.f}, acc1 = {0.f, 0.f, 0.f, 0.f};
#pragma unroll
    for (int ky = 0; ky < 3; ky++) {
      const int iy = 2 * oy + ky - 1;  // in [-1, HI-1]
      const __hip_bfloat16* rowp = inb + (size_t)(iy < 0 ? 0 : iy) * WI * 32;
#pragma unroll
      for (int kx = 0; kx < 3; kx++) {
        const int ix = 2 * (ox0 + r) + kx - 1;  // in [-1, WI-1]
        uint4 v = *(const uint4*)(rowp + (size_t)(ix < 0 ? 0 : ix) * 32 + g * 8);
        if ((iy | ix) < 0) { v.x = 0; v.y = 0; v.z = 0; v.w = 0; }
        bf16x8 a = *reinterpret_cast<const bf16x8*>(&v);
        acc0 = __builtin_amdgcn_mfma_f32_16x16x32_bf16(bw[ky * 3 + kx][0], a,
                                                       acc0, 0, 0, 0);
        acc1 = __builtin_amdgcn_mfma_f32_16x16x32_bf16(bw[ky * 3 + kx][1], a,
                                                       acc1, 0, 0, 0);
      }
    }
    const size_t opix = ((size_t)b * HO + oy) * WO + ox0 + r;
    unsigned msk = masku[opix] ? 0xFFFFFFFFu : 0u;
    uint4 o = quad_pack(acc0, acc1, msk);
    *(uint4*)(out + opix * 32 + 8 * g) = o;
  }
}

// ---- masked mean pool over 64x64, per batch ----
__global__ __launch_bounds__(256) void k_pool(const __hip_bfloat16* __restrict__ y4,
                                              const float* __restrict__ m4,
                                              float* __restrict__ pooled) {
  const int b = blockIdx.x, t = threadIdx.x;
  const int c8 = t & 3, g = t >> 2;
  float s[8] = {0, 0, 0, 0, 0, 0, 0, 0};
  for (int p = g; p < 4096; p += 64) {
    uint4 raw = *(const uint4*)(y4 + ((size_t)b * 4096 + p) * 32 + c8 * 8);
#pragma unroll
    for (int cp = 0; cp < 4; cp++) {
      unsigned w = comp(raw, cp);
      s[2 * cp] += bf_lo(w);
      s[2 * cp + 1] += bf_hi(w);
    }
  }
  __shared__ float s_red[64][32];
  __shared__ float s_cnt[256];
#pragma unroll
  for (int j = 0; j < 8; j++) s_red[g][c8 * 8 + j] = s[j];
  float cnt = 0;
  for (int p = t; p < 4096; p += 256) cnt += m4[(size_t)b * 4096 + p];
  s_cnt[t] = cnt;
  __syncthreads();
  for (int st = 32; st > 0; st >>= 1) {
    if (g < st) {
#pragma unroll
      for (int j = 0; j < 8; j++) s_red[g][c8 * 8 + j] += s_red[g + st][c8 * 8 + j];
    }
    __syncthreads();
  }
  for (int st = 128; st > 0; st >>= 1) {
    if (t < st) s_cnt[t] += s_cnt[t + st];
    __syncthreads();
  }
  if (t < 32) pooled[b * 32 + t] = s_red[0][t] / fmaxf(s_cnt[0], 1.f);
}

// ---- final MLP ----
__global__ __launch_bounds__(256) void k_mlp(
    const float* __restrict__ pooled, const float* __restrict__ x2,
    const float* __restrict__ W1, const float* __restrict__ b1,
    const float* __restrict__ W2, const float* __restrict__ b2,
    const float* __restrict__ W3, const float* __restrict__ b3,
    float* __restrict__ outp) {
  __shared__ float s_h1[8 * 64];
  __shared__ float s_z[8 * 64];
  const int t = threadIdx.x;
  for (int i = t; i < 512; i += 256) {
    int bb = i >> 6, j = i & 63;
    float a = b1[j] + x2[bb * 3 + 0] * W1[0 * 64 + j] +
              x2[bb * 3 + 1] * W1[1 * 64 + j] + x2[bb * 3 + 2] * W1[2 * 64 + j];
    s_h1[i] = fmaxf(a, 0.f);
  }
  __syncthreads();
  {
    int bb = t >> 5, ci = t & 31;
    float a = b2[ci];
    for (int k = 0; k < 64; k++) a += s_h1[bb * 64 + k] * W2[k * 32 + ci];
    s_z[bb * 64 + 32 + ci] = a;                // h part (no relu per reference)
    s_z[bb * 64 + ci] = pooled[bb * 32 + ci];  // pooled part
  }
  __syncthreads();
  for (int o = t; o < 1024; o += 256) {
    int bb = o >> 7, j = o & 127;
    float a = b3[j];
    for (int k = 0; k < 64; k++) a += s_z[bb * 64 + k] * W3[k * 128 + j];
    outp[o] = fmaxf(a, 0.f);
  }
}

// ---------------------------------------------------------------------------
extern "C" void kernel_launch(void* const* d_in, const int* in_sizes, int n_in,
                              void* d_out, int out_size, void* d_ws,
                              size_t ws_size, hipStream_t stream) {
  const int* coords = (const int*)d_in[0];
  const float* feats = (const float*)d_in[1];
  const float* x2 = (const float*)d_in[2];
  const float* K1 = (const float*)d_in[3];
  const float* K2 = (const float*)d_in[4];
  const float* K3 = (const float*)d_in[5];
  const float* K4 = (const float*)d_in[6];
  const float* W1 = (const float*)d_in[7];
  const float* b1 = (const float*)d_in[8];
  const float* W2 = (const float*)d_in[9];
  const float* b2 = (const float*)d_in[10];
  const float* W3 = (const float*)d_in[11];
  const float* b3 = (const float*)d_in[12];
  float* outp = (float*)d_out;

  char* ws = (char*)d_ws;
  size_t off = 0;
  auto alloc = [&](size_t bytes) {
    char* p = ws + off;
    off += (bytes + 255) & ~(size_t)255;
    return p;
  };
  int* idxg = (int*)alloc(8ull * 512 * 512 * 4);
  unsigned* grid2 = (unsigned*)alloc(8ull * 512 * 512 * 4);
  __hip_bfloat16* y2 = (__hip_bfloat16*)alloc(8ull * 256 * 256 * 32 * 2);
  __hip_bfloat16* y3 = (__hip_bfloat16*)alloc(8ull * 128 * 128 * 32 * 2);
  __hip_bfloat16* y4 = (__hip_bfloat16*)alloc(8ull * 64 * 64 * 32 * 2);
  float* m2 = (float*)alloc(8ull * 256 * 256 * 4);
  float* m3 = (float*)alloc(8ull * 128 * 128 * 4);
  float* m4 = (float*)alloc(8ull * 64 * 64 * 4);
  float* pooled = (float*)alloc(8 * 32 * 4);
  unsigned short* pw1h = (unsigned short*)alloc(128 * 8 * 2);
  unsigned short* pw1l = (unsigned short*)alloc(128 * 8 * 2);
  unsigned short* pw2 = (unsigned short*)alloc(1152 * 8 * 2);
  unsigned short* pw3 = (unsigned short*)alloc(1152 * 8 * 2);
  unsigned short* pw4 = (unsigned short*)alloc(1152 * 8 * 2);
  (void)ws_size; (void)in_sizes; (void)n_in; (void)out_size;

  (void)hipMemsetAsync(idxg, 0xFF, 8ull * 512 * 512 * 4, stream);  // idx = -1

  k_scatter<<<NPTS / 256, 256, 0, stream>>>(coords, idxg);
  k_grid<<<(8 * 512 * 512) / 256, 256, 0, stream>>>(idxg, feats, grid2);
  k_masks<<<dim3(8, 8, 8), 256, 0, stream>>>(idxg, m2, m3, m4, K1, K2, K3, K4,
                                             pw1h, pw1l, pw2, pw3, pw4);

  // fused conv1+conv2: y2 tile 8x16 per block
  k_conv12<<<dim3(16, 32, 8), 256, 0, stream>>>(grid2, idxg, pw1h, pw1l, pw2,
                                                m2, y2);

  k_conv3x3s2_mfma<256, 4, 2><<<dim3(4, 64, 8), 128, 0, stream>>>(y2, pw3, m3, y3);
  k_conv3x3s2_mfma<128, 4, 1><<<dim3(4, 64, 8), 64, 0, stream>>>(y3, pw4, m4, y4);

  k_pool<<<8, 256, 0, stream>>>(y4, m4, pooled);
  k_mlp<<<1, 256, 0, stream>>>(pooled, x2, W1, b1, W2, b2, W3, b3, outp);
}